// Round 7
// baseline (6217.218 us; speedup 1.0000x reference)
//
#include <hip/hip_runtime.h>
#include <hip/hip_bf16.h>
#include <cmath>

#define S 2048
#define HID 4096
#define NH 32
#define NKVH 8
#define DH 128
#define LAST 20
#define BLOCK_TOK 32
#define NBLK 64  /* S / BLOCK_TOK */
#define QB 32    /* flash q-tile */

typedef __attribute__((ext_vector_type(8))) short bf16x8;
typedef __attribute__((ext_vector_type(4))) float f32x4;

static __device__ __forceinline__ unsigned short f2bf_rne(float x) {
    unsigned int u = __float_as_uint(x);
    unsigned int r = (u + 0x7FFFu + ((u >> 16) & 1u)) >> 16;
    return (unsigned short)r;
}
static __device__ __forceinline__ float bf2f(unsigned short h) {
    return __uint_as_float(((unsigned int)h) << 16);
}

// ---------------------------------------------------------------------------
// Split-bf16 MFMA GEMM (post-decision paths: Q-proj, O-proj). VALIDATED r6.
// C ~= Ah*Bh + Al*Bh + Ah*Bl, err ~1e-5 relative. 128x128, BK=32, 4 waves.
// ---------------------------------------------------------------------------
__global__ __launch_bounds__(256) void gemm_split(const float* __restrict__ A,
                                                  const float* __restrict__ B,
                                                  float* __restrict__ C,
                                                  int M, int N, int K) {
    __shared__ __align__(16) unsigned char smem[32768];
    unsigned char* Ab = smem;
    unsigned char* Bb = smem + 16384;
    const int tid = threadIdx.x;
    const int bx = blockIdx.x * 128;
    const int by = blockIdx.y * 128;
    const int lane = tid & 63, wid = tid >> 6;
    const int wm = wid >> 1, wn = wid & 1;
    const int l15 = lane & 15, lg = lane >> 4;

    const int ar = tid >> 1, akh = tid & 1;
    const int bcol = tid & 127, bks = tid >> 7;

    f32x4 acc[4][4];
    #pragma unroll
    for (int i = 0; i < 4; ++i)
        #pragma unroll
        for (int j = 0; j < 4; ++j)
            acc[i][j] = (f32x4){0.f, 0.f, 0.f, 0.f};

    for (int k0 = 0; k0 < K; k0 += 32) {
        {
            const float* ap = A + (size_t)(by + ar) * K + k0 + akh * 16;
            float fv[16];
            #pragma unroll
            for (int j = 0; j < 4; ++j) {
                float4 t4 = *reinterpret_cast<const float4*>(ap + 4 * j);
                fv[4 * j + 0] = t4.x; fv[4 * j + 1] = t4.y;
                fv[4 * j + 2] = t4.z; fv[4 * j + 3] = t4.w;
            }
            unsigned short hi[16], lo[16];
            #pragma unroll
            for (int j = 0; j < 16; ++j) {
                hi[j] = f2bf_rne(fv[j]);
                lo[j] = f2bf_rne(fv[j] - bf2f(hi[j]));
            }
            uint4 w;
            unsigned char* rp = Ab + ar * 128;
            const int m7 = ar & 7;
            w.x = (unsigned)hi[0] | ((unsigned)hi[1] << 16);
            w.y = (unsigned)hi[2] | ((unsigned)hi[3] << 16);
            w.z = (unsigned)hi[4] | ((unsigned)hi[5] << 16);
            w.w = (unsigned)hi[6] | ((unsigned)hi[7] << 16);
            *reinterpret_cast<uint4*>(rp + (((akh * 2 + 0) ^ m7) << 4)) = w;
            w.x = (unsigned)hi[8]  | ((unsigned)hi[9]  << 16);
            w.y = (unsigned)hi[10] | ((unsigned)hi[11] << 16);
            w.z = (unsigned)hi[12] | ((unsigned)hi[13] << 16);
            w.w = (unsigned)hi[14] | ((unsigned)hi[15] << 16);
            *reinterpret_cast<uint4*>(rp + (((akh * 2 + 1) ^ m7) << 4)) = w;
            w.x = (unsigned)lo[0] | ((unsigned)lo[1] << 16);
            w.y = (unsigned)lo[2] | ((unsigned)lo[3] << 16);
            w.z = (unsigned)lo[4] | ((unsigned)lo[5] << 16);
            w.w = (unsigned)lo[6] | ((unsigned)lo[7] << 16);
            *reinterpret_cast<uint4*>(rp + (((akh * 2 + 4) ^ m7) << 4)) = w;
            w.x = (unsigned)lo[8]  | ((unsigned)lo[9]  << 16);
            w.y = (unsigned)lo[10] | ((unsigned)lo[11] << 16);
            w.z = (unsigned)lo[12] | ((unsigned)lo[13] << 16);
            w.w = (unsigned)lo[14] | ((unsigned)lo[15] << 16);
            *reinterpret_cast<uint4*>(rp + (((akh * 2 + 5) ^ m7) << 4)) = w;
        }
        {
            const float* bp = B + (size_t)(k0 + bks * 16) * N + bx + bcol;
            float fv[16];
            #pragma unroll
            for (int j = 0; j < 16; ++j) fv[j] = bp[(size_t)j * N];
            unsigned short hi[16], lo[16];
            #pragma unroll
            for (int j = 0; j < 16; ++j) {
                hi[j] = f2bf_rne(fv[j]);
                lo[j] = f2bf_rne(fv[j] - bf2f(hi[j]));
            }
            uint4 w;
            unsigned char* cp = Bb + bcol * 128;
            const int m7 = bcol & 7;
            w.x = (unsigned)hi[0] | ((unsigned)hi[1] << 16);
            w.y = (unsigned)hi[2] | ((unsigned)hi[3] << 16);
            w.z = (unsigned)hi[4] | ((unsigned)hi[5] << 16);
            w.w = (unsigned)hi[6] | ((unsigned)hi[7] << 16);
            *reinterpret_cast<uint4*>(cp + (((bks * 2 + 0) ^ m7) << 4)) = w;
            w.x = (unsigned)hi[8]  | ((unsigned)hi[9]  << 16);
            w.y = (unsigned)hi[10] | ((unsigned)hi[11] << 16);
            w.z = (unsigned)hi[12] | ((unsigned)hi[13] << 16);
            w.w = (unsigned)hi[14] | ((unsigned)hi[15] << 16);
            *reinterpret_cast<uint4*>(cp + (((bks * 2 + 1) ^ m7) << 4)) = w;
            w.x = (unsigned)lo[0] | ((unsigned)lo[1] << 16);
            w.y = (unsigned)lo[2] | ((unsigned)lo[3] << 16);
            w.z = (unsigned)lo[4] | ((unsigned)lo[5] << 16);
            w.w = (unsigned)lo[6] | ((unsigned)lo[7] << 16);
            *reinterpret_cast<uint4*>(cp + (((bks * 2 + 4) ^ m7) << 4)) = w;
            w.x = (unsigned)lo[8]  | ((unsigned)lo[9]  << 16);
            w.y = (unsigned)lo[10] | ((unsigned)lo[11] << 16);
            w.z = (unsigned)lo[12] | ((unsigned)lo[13] << 16);
            w.w = (unsigned)lo[14] | ((unsigned)lo[15] << 16);
            *reinterpret_cast<uint4*>(cp + (((bks * 2 + 5) ^ m7) << 4)) = w;
        }
        __syncthreads();
        bf16x8 ah[4], al[4], bh[4], bl[4];
        #pragma unroll
        for (int f = 0; f < 4; ++f) {
            const int R = wm * 64 + f * 16 + l15;
            const unsigned char* rp = Ab + R * 128;
            const int m7 = R & 7;
            ah[f] = *reinterpret_cast<const bf16x8*>(rp + ((lg ^ m7) << 4));
            al[f] = *reinterpret_cast<const bf16x8*>(rp + (((lg + 4) ^ m7) << 4));
            const int Cc = wn * 64 + f * 16 + l15;
            const unsigned char* cp = Bb + Cc * 128;
            const int c7 = Cc & 7;
            bh[f] = *reinterpret_cast<const bf16x8*>(cp + ((lg ^ c7) << 4));
            bl[f] = *reinterpret_cast<const bf16x8*>(cp + (((lg + 4) ^ c7) << 4));
        }
        __syncthreads();
        #pragma unroll
        for (int mf = 0; mf < 4; ++mf)
            #pragma unroll
            for (int nf = 0; nf < 4; ++nf) {
                acc[mf][nf] = __builtin_amdgcn_mfma_f32_16x16x32_bf16(
                    ah[mf], bh[nf], acc[mf][nf], 0, 0, 0);
                acc[mf][nf] = __builtin_amdgcn_mfma_f32_16x16x32_bf16(
                    al[mf], bh[nf], acc[mf][nf], 0, 0, 0);
                acc[mf][nf] = __builtin_amdgcn_mfma_f32_16x16x32_bf16(
                    ah[mf], bl[nf], acc[mf][nf], 0, 0, 0);
            }
    }
    #pragma unroll
    for (int mf = 0; mf < 4; ++mf) {
        #pragma unroll
        for (int nf = 0; nf < 4; ++nf) {
            const int col = bx + wn * 64 + nf * 16 + l15;
            #pragma unroll
            for (int r = 0; r < 4; ++r) {
                const int row = by + wm * 64 + mf * 16 + lg * 4 + r;
                C[(size_t)row * N + col] = acc[mf][nf][r];
            }
        }
    }
}

// ---------------------------------------------------------------------------
// f64-accumulation GEMM for decision path (K,V): C_f64 = A_f32 @ B_f32.
// f32xf32 products are exact in f64; sum error ~1e-13 rel -> no rint flips.
// 64x64 tile, BK=16, 4x4 f64 micro-tile.
// ---------------------------------------------------------------------------
__global__ __launch_bounds__(256) void gemm_f64acc(const float* __restrict__ A,
                                                   const float* __restrict__ B,
                                                   double* __restrict__ C,
                                                   int M, int N, int K) {
    const int BM = 64, BN = 64, BK = 16;
    __shared__ double As[BK][BM + 2];
    __shared__ double Bs[BK][BN + 2];
    const int tid = threadIdx.x;
    const int tx = tid & 15, ty = tid >> 4;
    const int bx = blockIdx.x * BN, by = blockIdx.y * BM;

    double acc[4][4] = {};

    for (int k0 = 0; k0 < K; k0 += BK) {
        #pragma unroll
        for (int i = 0; i < 4; ++i) {
            int idx = tid + i * 256;            // 0..1023
            int ar = idx >> 4, ac = idx & 15;
            As[ac][ar] = (double)A[(size_t)(by + ar) * K + k0 + ac];
            int br = idx >> 6, bc = idx & 63;
            Bs[br][bc] = (double)B[(size_t)(k0 + br) * N + bx + bc];
        }
        __syncthreads();
        #pragma unroll
        for (int kk = 0; kk < BK; ++kk) {
            double av[4], bv[4];
            #pragma unroll
            for (int i = 0; i < 4; ++i) { av[i] = As[kk][ty * 4 + i]; bv[i] = Bs[kk][tx * 4 + i]; }
            #pragma unroll
            for (int i = 0; i < 4; ++i)
                #pragma unroll
                for (int j = 0; j < 4; ++j)
                    acc[i][j] = fma(av[i], bv[j], acc[i][j]);
        }
        __syncthreads();
    }
    #pragma unroll
    for (int i = 0; i < 4; ++i)
        #pragma unroll
        for (int j = 0; j < 4; ++j)
            C[(size_t)(by + ty * 4 + i) * N + bx + tx * 4 + j] = acc[i][j];
}

// ---------------------------------------------------------------------------
// RoPE: q (f32, in place) and kD (f64, in place).
// ---------------------------------------------------------------------------
__global__ __launch_bounds__(256) void rope_q(float* __restrict__ q,
                                              const float* __restrict__ cosT,
                                              const float* __restrict__ sinT) {
    int idx = blockIdx.x * 256 + threadIdx.x;       // S*NH*64
    int t = idx / (NH * 64);
    int rem = idx % (NH * 64);
    int h = rem >> 6, d = rem & 63;
    float c1 = cosT[t * DH + d], s1 = sinT[t * DH + d];
    float c2 = cosT[t * DH + d + 64], s2 = sinT[t * DH + d + 64];
    float* base = q + (size_t)t * HID + h * DH;
    float x1 = base[d], x2 = base[d + 64];
    base[d]      = x1 * c1 - x2 * s1;
    base[d + 64] = x2 * c2 + x1 * s2;
}

__global__ __launch_bounds__(256) void rope_kD(double* __restrict__ kD,
                                               const float* __restrict__ cosT,
                                               const float* __restrict__ sinT) {
    int idx = blockIdx.x * 256 + threadIdx.x;       // S*NKVH*64
    int t = idx / (NKVH * 64);
    int rem = idx % (NKVH * 64);
    int h = rem >> 6, d = rem & 63;
    double c1 = (double)cosT[t * DH + d], s1 = (double)sinT[t * DH + d];
    double c2 = (double)cosT[t * DH + d + 64], s2 = (double)sinT[t * DH + d + 64];
    double* base = kD + ((size_t)t * NKVH + h) * DH;
    double x1 = base[d], x2 = base[d + 64];
    base[d]      = x1 * c1 - x2 * s1;
    base[d + 64] = x2 * c2 + x1 * s2;
}

// ---------------------------------------------------------------------------
// Importance chain, f64. One block per head: recompute last-20 q rows in f64,
// RoPE them, score vs kD, softmax f64, accumulate per-head timp partials.
// ---------------------------------------------------------------------------
__global__ __launch_bounds__(256) void imp_head(const float* __restrict__ hs,
                                                const float* __restrict__ Wq,
                                                const double* __restrict__ kD,
                                                const float* __restrict__ cosT,
                                                const float* __restrict__ sinT,
                                                double* __restrict__ hpart) {
    const int h = blockIdx.x;
    const int kvh = h >> 2;
    const int tid = threadIdx.x;
    const int lane = tid & 63, wid = tid >> 6;
    __shared__ double qD[LAST][DH];     // 20 KiB
    __shared__ double timp[S];          // 16 KiB
    __shared__ double redA[4], redB[4];

    // last-20 q rows in f64
    for (int e = tid; e < LAST * DH; e += 256) {
        int j = e >> 7, d = e & 127;
        const float* arow = hs + (size_t)(S - LAST + j) * HID;
        const size_t coff = (size_t)h * DH + d;
        double s = 0.0;
        for (int m = 0; m < HID; ++m)
            s = fma((double)arow[m], (double)Wq[(size_t)m * HID + coff], s);
        qD[j][d] = s;
    }
    __syncthreads();
    // RoPE in f64 (pairwise, no cross-thread overlap)
    for (int e = tid; e < LAST * 64; e += 256) {
        int j = e >> 6, d = e & 63;
        int t = S - LAST + j;
        double c1 = (double)cosT[t * DH + d], s1 = (double)sinT[t * DH + d];
        double c2 = (double)cosT[t * DH + d + 64], s2 = (double)sinT[t * DH + d + 64];
        double x1 = qD[j][d], x2 = qD[j][d + 64];
        qD[j][d]      = x1 * c1 - x2 * s1;
        qD[j][d + 64] = x2 * c2 + x1 * s2;
    }
    for (int i = tid; i < S; i += 256) timp[i] = 0.0;
    __syncthreads();

    const double SC = 0.08838834764831843;  // 128^-0.5
    for (int j = 0; j < LAST; ++j) {
        const int qpos = S - LAST + j;
        const int nk = qpos + 1;
        double sloc[8];
        int cnt = 0;
        double lmax = -1e300;
        for (int kp = tid; kp < nk; kp += 256) {
            const double* kr = kD + ((size_t)kp * NKVH + kvh) * DH;
            double s = 0.0;
            #pragma unroll 8
            for (int d = 0; d < DH; ++d) s = fma(qD[j][d], kr[d], s);
            s *= SC;
            sloc[cnt++] = s;
            lmax = fmax(lmax, s);
        }
        #pragma unroll
        for (int o = 32; o > 0; o >>= 1) lmax = fmax(lmax, __shfl_xor(lmax, o));
        if (lane == 0) redA[wid] = lmax;
        __syncthreads();
        double gmax = fmax(fmax(redA[0], redA[1]), fmax(redA[2], redA[3]));
        double lsum = 0.0;
        for (int i = 0; i < cnt; ++i) lsum += exp(sloc[i] - gmax);
        #pragma unroll
        for (int o = 32; o > 0; o >>= 1) lsum += __shfl_xor(lsum, o);
        if (lane == 0) redB[wid] = lsum;
        __syncthreads();
        double inv = 1.0 / (redB[0] + redB[1] + redB[2] + redB[3]);
        int i = 0;
        for (int kp = tid; kp < nk; kp += 256, ++i) timp[kp] += exp(sloc[i] - gmax) * inv;
        __syncthreads();
    }
    for (int i = tid; i < S; i += 256) hpart[(size_t)h * S + i] = timp[i];
}

__global__ __launch_bounds__(256) void imp_finish(const double* __restrict__ hpart,
                                                  double* __restrict__ timpD) {
    int kp = blockIdx.x * 256 + threadIdx.x;
    double s = 0.0;
    for (int h = 0; h < NH; ++h) s += hpart[(size_t)h * S + kp];
    int cntv = (kp >= S - LAST) ? (S - kp) : LAST;
    timpD[kp] = s / (double)cntv;
}

// ---------------------------------------------------------------------------
// Block importance (f64) -> stable descending argsort -> per-token levels.
// ---------------------------------------------------------------------------
__global__ __launch_bounds__(64) void bits_alloc(const double* __restrict__ timpD,
                                                 const float* __restrict__ ratio,
                                                 float* __restrict__ levels_tok) {
    __shared__ double bimp[NBLK];
    __shared__ int bbits[NBLK];
    __shared__ unsigned char taken[NBLK];
    int tid = threadIdx.x;
    double s = 0.0;
    for (int i = 0; i < BLOCK_TOK; ++i) s += timpD[tid * BLOCK_TOK + i];
    bimp[tid] = s;
    taken[tid] = 0;
    __syncthreads();
    if (tid == 0) {
        int kb[4], tot = 0;
        for (int g = 0; g < 4; ++g) { kb[g] = (int)rint(64.0 * (double)ratio[g]); tot += kb[g]; }
        kb[3] += NBLK - tot;
        int c0 = kb[0], c1 = kb[0] + kb[1], c2 = kb[0] + kb[1] + kb[2];
        for (int r = 0; r < NBLK; ++r) {
            int best = -1; double bv = 0.0;
            for (int b2 = 0; b2 < NBLK; ++b2) {
                if (!taken[b2] && (best < 0 || bimp[b2] > bv)) { bv = bimp[b2]; best = b2; }
            }
            taken[best] = 1;
            int g = (r >= c0) + (r >= c1) + (r >= c2);  // searchsorted 'right'
            bbits[best] = 8 >> g;                        // BITS = {8,4,2,1}
        }
    }
    __syncthreads();
    float lev = (float)((1 << bbits[tid]) - 1);
    for (int i = 0; i < BLOCK_TOK; ++i) levels_tok[tid * BLOCK_TOK + i] = lev;
}

// ---------------------------------------------------------------------------
// Fake quant in f64, narrowing in place: each row's 128 f64 -> 128 f32 at the
// row base. One wave per (token, kv-head) row; handles k then v.
// ---------------------------------------------------------------------------
__global__ __launch_bounds__(64) void fakequant(double* __restrict__ kD,
                                                double* __restrict__ vD,
                                                const float* __restrict__ levels_tok) {
    int row = blockIdx.x;                      // t*NKVH + kvh
    double lev = (double)levels_tok[row >> 3]; // per-token level
    int lane = threadIdx.x;
    #pragma unroll
    for (int which = 0; which < 2; ++which) {
        double* p = (which ? vD : kD) + (size_t)row * DH;
        double x0 = p[lane], x1 = p[lane + 64];
        double mn = fmin(x0, x1), mx = fmax(x0, x1);
        #pragma unroll
        for (int o = 1; o < 64; o <<= 1) {
            mn = fmin(mn, __shfl_xor(mn, o));
            mx = fmax(mx, __shfl_xor(mx, o));
        }
        double scale = fmax((mx - mn) / lev, 1e-8);
        double q0 = rint((x0 - mn) / scale) * scale + mn;
        double q1 = rint((x1 - mn) / scale) * scale + mn;
        __syncthreads();   // all f64 reads complete before f32 overwrite
        float* f = (float*)p;
        f[lane]      = (float)q0;
        f[lane + 64] = (float)q1;
        __syncthreads();
    }
}

// ---------------------------------------------------------------------------
// Flash attention over quantized KV (f32 views, row stride 256 floats).
// ctx written IN PLACE over q (block-local region only).
// ---------------------------------------------------------------------------
__global__ __launch_bounds__(256) void attn_flash(float* __restrict__ q,
                                                  const float* __restrict__ kf,
                                                  const float* __restrict__ vf) {
    const float SCALING = 0.08838834764831843f;
    const int h = blockIdx.x;
    const int qt = blockIdx.y;
    const int q0 = qt * QB;
    const int kvh = h >> 2;
    __shared__ float Qs[QB][DH + 4];
    __shared__ float Ks[QB][DH + 4];
    __shared__ float Vs[QB][DH + 4];
    __shared__ float Ps[QB][QB + 1];
    const int tid = threadIdx.x;
    const int tq = tid >> 4;
    const int tg = tid & 15;

    {
        int r = tid >> 3, c = (tid & 7) * 16;
        const float* src = &q[(size_t)(q0 + r) * HID + h * DH + c];
        #pragma unroll
        for (int j = 0; j < 4; ++j)
            *reinterpret_cast<float4*>(&Qs[r][c + 4 * j]) =
                *reinterpret_cast<const float4*>(&src[4 * j]);
    }
    float m0 = -INFINITY, m1 = -INFINITY, l0 = 0.f, l1 = 0.f;
    float acc0[8] = {}, acc1[8] = {};
    __syncthreads();

    for (int kt = 0; kt <= qt; ++kt) {
        const int kbase = kt * QB;
        {
            int r = tid >> 3, c = (tid & 7) * 16;
            const float* ksrc = kf + ((((size_t)(kbase + r)) * NKVH + kvh) << 8) + c;
            const float* vsrc = vf + ((((size_t)(kbase + r)) * NKVH + kvh) << 8) + c;
            #pragma unroll
            for (int j = 0; j < 4; ++j) {
                *reinterpret_cast<float4*>(&Ks[r][c + 4 * j]) =
                    *reinterpret_cast<const float4*>(&ksrc[4 * j]);
                *reinterpret_cast<float4*>(&Vs[r][c + 4 * j]) =
                    *reinterpret_cast<const float4*>(&vsrc[4 * j]);
            }
        }
        __syncthreads();

        float s00 = 0.f, s01 = 0.f, s10 = 0.f, s11 = 0.f;
        #pragma unroll 8
        for (int dc = 0; dc < DH; dc += 4) {
            float4 qa = *reinterpret_cast<const float4*>(&Qs[tq][dc]);
            float4 qb = *reinterpret_cast<const float4*>(&Qs[tq + 16][dc]);
            float4 ka = *reinterpret_cast<const float4*>(&Ks[tg][dc]);
            float4 kb = *reinterpret_cast<const float4*>(&Ks[tg + 16][dc]);
            s00 += qa.x * ka.x + qa.y * ka.y + qa.z * ka.z + qa.w * ka.w;
            s01 += qa.x * kb.x + qa.y * kb.y + qa.z * kb.z + qa.w * kb.w;
            s10 += qb.x * ka.x + qb.y * ka.y + qb.z * ka.z + qb.w * ka.w;
            s11 += qb.x * kb.x + qb.y * kb.y + qb.z * kb.z + qb.w * kb.w;
        }
        s00 *= SCALING; s01 *= SCALING; s10 *= SCALING; s11 *= SCALING;
        const int qg0 = q0 + tq, qg1 = q0 + tq + 16;
        const int k0g = kbase + tg, k1g = kbase + tg + 16;
        if (k0g > qg0) s00 = -INFINITY;
        if (k1g > qg0) s01 = -INFINITY;
        if (k0g > qg1) s10 = -INFINITY;
        if (k1g > qg1) s11 = -INFINITY;

        float t0 = fmaxf(s00, s01), t1 = fmaxf(s10, s11);
        #pragma unroll
        for (int o = 1; o < 16; o <<= 1) {
            t0 = fmaxf(t0, __shfl_xor(t0, o));
            t1 = fmaxf(t1, __shfl_xor(t1, o));
        }
        float mn0 = fmaxf(m0, t0), mn1 = fmaxf(m1, t1);
        float c0 = expf(m0 - mn0), c1 = expf(m1 - mn1);
        float p00 = expf(s00 - mn0), p01 = expf(s01 - mn0);
        float p10 = expf(s10 - mn1), p11 = expf(s11 - mn1);
        float u0 = p00 + p01, u1 = p10 + p11;
        #pragma unroll
        for (int o = 1; o < 16; o <<= 1) {
            u0 += __shfl_xor(u0, o);
            u1 += __shfl_xor(u1, o);
        }
        l0 = l0 * c0 + u0; l1 = l1 * c1 + u1;
        m0 = mn0; m1 = mn1;
        Ps[tq][tg] = p00;      Ps[tq][tg + 16] = p01;
        Ps[tq + 16][tg] = p10; Ps[tq + 16][tg + 16] = p11;
        #pragma unroll
        for (int j = 0; j < 8; ++j) { acc0[j] *= c0; acc1[j] *= c1; }
        __syncthreads();

        #pragma unroll 4
        for (int kk = 0; kk < QB; ++kk) {
            float p0 = Ps[tq][kk], p1 = Ps[tq + 16][kk];
            float4 v0 = *reinterpret_cast<const float4*>(&Vs[kk][tg * 4]);
            float4 v1 = *reinterpret_cast<const float4*>(&Vs[kk][64 + tg * 4]);
            acc0[0] = fmaf(p0, v0.x, acc0[0]); acc0[1] = fmaf(p0, v0.y, acc0[1]);
            acc0[2] = fmaf(p0, v0.z, acc0[2]); acc0[3] = fmaf(p0, v0.w, acc0[3]);
            acc0[4] = fmaf(p0, v1.x, acc0[4]); acc0[5] = fmaf(p0, v1.y, acc0[5]);
            acc0[6] = fmaf(p0, v1.z, acc0[6]); acc0[7] = fmaf(p0, v1.w, acc0[7]);
            acc1[0] = fmaf(p1, v0.x, acc1[0]); acc1[1] = fmaf(p1, v0.y, acc1[1]);
            acc1[2] = fmaf(p1, v0.z, acc1[2]); acc1[3] = fmaf(p1, v0.w, acc1[3]);
            acc1[4] = fmaf(p1, v1.x, acc1[4]); acc1[5] = fmaf(p1, v1.y, acc1[5]);
            acc1[6] = fmaf(p1, v1.z, acc1[6]); acc1[7] = fmaf(p1, v1.w, acc1[7]);
        }
        __syncthreads();
    }

    float i0 = 1.0f / l0, i1 = 1.0f / l1;
    float* o0 = &q[(size_t)(q0 + tq) * HID + h * DH];        // in-place ctx
    float* o1 = &q[(size_t)(q0 + tq + 16) * HID + h * DH];
    float4 w;
    w = make_float4(acc0[0] * i0, acc0[1] * i0, acc0[2] * i0, acc0[3] * i0);
    *reinterpret_cast<float4*>(&o0[tg * 4]) = w;
    w = make_float4(acc0[4] * i0, acc0[5] * i0, acc0[6] * i0, acc0[7] * i0);
    *reinterpret_cast<float4*>(&o0[64 + tg * 4]) = w;
    w = make_float4(acc1[0] * i1, acc1[1] * i1, acc1[2] * i1, acc1[3] * i1);
    *reinterpret_cast<float4*>(&o1[tg * 4]) = w;
    w = make_float4(acc1[4] * i1, acc1[5] * i1, acc1[6] * i1, acc1[7] * i1);
    *reinterpret_cast<float4*>(&o1[64 + tg * 4]) = w;
}

// ---------------------------------------------------------------------------
extern "C" void kernel_launch(void* const* d_in, const int* in_sizes, int n_in,
                              void* d_out, int out_size, void* d_ws, size_t ws_size,
                              hipStream_t stream) {
    const float* hs    = (const float*)d_in[0];
    const float* cosT  = (const float*)d_in[1];
    const float* sinT  = (const float*)d_in[2];
    /* d_in[3] attention_mask: pure causal, reconstructed analytically */
    const float* ratio = (const float*)d_in[4];
    const float* Wq    = (const float*)d_in[5];
    const float* Wk    = (const float*)d_in[6];
    const float* Wv    = (const float*)d_in[7];
    const float* Wo    = (const float*)d_in[8];
    float* out = (float*)d_out;

    // ws layout: doubles first, then floats. Total ~68 MB.
    double* kD    = (double*)d_ws;                       // S*NKVH*DH  f64
    double* vD    = kD + (size_t)S * NKVH * DH;          // S*NKVH*DH  f64
    double* hpart = vD + (size_t)S * NKVH * DH;          // NH*S       f64
    double* timpD = hpart + (size_t)NH * S;              // S          f64
    float*  qbuf  = (float*)(timpD + S);                 // S*HID      f32 (q, then ctx in place)
    float*  levels = qbuf + (size_t)S * HID;             // S          f32

    dim3 blk(256);
    // Q projection: post-decision -> split-bf16 MFMA (validated r6).
    gemm_split<<<dim3(HID / 128, S / 128), blk, 0, stream>>>(hs, Wq, qbuf, S, HID, HID);
    // K,V projections: decision path -> f64 accumulation.
    gemm_f64acc<<<dim3((NKVH * DH) / 64, S / 64), blk, 0, stream>>>(hs, Wk, kD, S, NKVH * DH, HID);
    gemm_f64acc<<<dim3((NKVH * DH) / 64, S / 64), blk, 0, stream>>>(hs, Wv, vD, S, NKVH * DH, HID);

    rope_q<<<(S * NH * 64) / 256, blk, 0, stream>>>(qbuf, cosT, sinT);
    rope_kD<<<(S * NKVH * 64) / 256, blk, 0, stream>>>(kD, cosT, sinT);

    imp_head<<<NH, blk, 0, stream>>>(hs, Wq, kD, cosT, sinT, hpart);
    imp_finish<<<S / 256, blk, 0, stream>>>(hpart, timpD);
    bits_alloc<<<1, 64, 0, stream>>>(timpD, ratio, levels);
    fakequant<<<S * NKVH, 64, 0, stream>>>(kD, vD, levels);

    attn_flash<<<dim3(NH, S / QB), blk, 0, stream>>>(qbuf, (const float*)kD, (const float*)vD);

    // Output projection: split-bf16 MFMA on ctx (= qbuf after attention).
    gemm_split<<<dim3(HID / 128, S / 128), blk, 0, stream>>>(qbuf, Wo, out, S, HID, HID);
}

// Round 8
// 3223.998 us; speedup vs baseline: 1.9284x; 1.9284x over previous
//
#include <hip/hip_runtime.h>
#include <hip/hip_bf16.h>
#include <cmath>

#define S 2048
#define HID 4096
#define NH 32
#define NKVH 8
#define DH 128
#define LAST 20
#define BLOCK_TOK 32
#define NBLK 64  /* S / BLOCK_TOK */
#define QB 32    /* flash q-tile */

typedef __attribute__((ext_vector_type(8))) short bf16x8;
typedef __attribute__((ext_vector_type(4))) float f32x4;

static __device__ __forceinline__ unsigned short f2bf_rne(float x) {
    unsigned int u = __float_as_uint(x);
    unsigned int r = (u + 0x7FFFu + ((u >> 16) & 1u)) >> 16;
    return (unsigned short)r;
}
static __device__ __forceinline__ float bf2f(unsigned short h) {
    return __uint_as_float(((unsigned int)h) << 16);
}

// ---------------------------------------------------------------------------
// Split-bf16 MFMA GEMM (post-decision paths: Q-proj, O-proj). VALIDATED r6/r7.
// ---------------------------------------------------------------------------
__global__ __launch_bounds__(256) void gemm_split(const float* __restrict__ A,
                                                  const float* __restrict__ B,
                                                  float* __restrict__ C,
                                                  int M, int N, int K) {
    __shared__ __align__(16) unsigned char smem[32768];
    unsigned char* Ab = smem;
    unsigned char* Bb = smem + 16384;
    const int tid = threadIdx.x;
    const int bx = blockIdx.x * 128;
    const int by = blockIdx.y * 128;
    const int lane = tid & 63, wid = tid >> 6;
    const int wm = wid >> 1, wn = wid & 1;
    const int l15 = lane & 15, lg = lane >> 4;

    const int ar = tid >> 1, akh = tid & 1;
    const int bcol = tid & 127, bks = tid >> 7;

    f32x4 acc[4][4];
    #pragma unroll
    for (int i = 0; i < 4; ++i)
        #pragma unroll
        for (int j = 0; j < 4; ++j)
            acc[i][j] = (f32x4){0.f, 0.f, 0.f, 0.f};

    for (int k0 = 0; k0 < K; k0 += 32) {
        {
            const float* ap = A + (size_t)(by + ar) * K + k0 + akh * 16;
            float fv[16];
            #pragma unroll
            for (int j = 0; j < 4; ++j) {
                float4 t4 = *reinterpret_cast<const float4*>(ap + 4 * j);
                fv[4 * j + 0] = t4.x; fv[4 * j + 1] = t4.y;
                fv[4 * j + 2] = t4.z; fv[4 * j + 3] = t4.w;
            }
            unsigned short hi[16], lo[16];
            #pragma unroll
            for (int j = 0; j < 16; ++j) {
                hi[j] = f2bf_rne(fv[j]);
                lo[j] = f2bf_rne(fv[j] - bf2f(hi[j]));
            }
            uint4 w;
            unsigned char* rp = Ab + ar * 128;
            const int m7 = ar & 7;
            w.x = (unsigned)hi[0] | ((unsigned)hi[1] << 16);
            w.y = (unsigned)hi[2] | ((unsigned)hi[3] << 16);
            w.z = (unsigned)hi[4] | ((unsigned)hi[5] << 16);
            w.w = (unsigned)hi[6] | ((unsigned)hi[7] << 16);
            *reinterpret_cast<uint4*>(rp + (((akh * 2 + 0) ^ m7) << 4)) = w;
            w.x = (unsigned)hi[8]  | ((unsigned)hi[9]  << 16);
            w.y = (unsigned)hi[10] | ((unsigned)hi[11] << 16);
            w.z = (unsigned)hi[12] | ((unsigned)hi[13] << 16);
            w.w = (unsigned)hi[14] | ((unsigned)hi[15] << 16);
            *reinterpret_cast<uint4*>(rp + (((akh * 2 + 1) ^ m7) << 4)) = w;
            w.x = (unsigned)lo[0] | ((unsigned)lo[1] << 16);
            w.y = (unsigned)lo[2] | ((unsigned)lo[3] << 16);
            w.z = (unsigned)lo[4] | ((unsigned)lo[5] << 16);
            w.w = (unsigned)lo[6] | ((unsigned)lo[7] << 16);
            *reinterpret_cast<uint4*>(rp + (((akh * 2 + 4) ^ m7) << 4)) = w;
            w.x = (unsigned)lo[8]  | ((unsigned)lo[9]  << 16);
            w.y = (unsigned)lo[10] | ((unsigned)lo[11] << 16);
            w.z = (unsigned)lo[12] | ((unsigned)lo[13] << 16);
            w.w = (unsigned)lo[14] | ((unsigned)lo[15] << 16);
            *reinterpret_cast<uint4*>(rp + (((akh * 2 + 5) ^ m7) << 4)) = w;
        }
        {
            const float* bp = B + (size_t)(k0 + bks * 16) * N + bx + bcol;
            float fv[16];
            #pragma unroll
            for (int j = 0; j < 16; ++j) fv[j] = bp[(size_t)j * N];
            unsigned short hi[16], lo[16];
            #pragma unroll
            for (int j = 0; j < 16; ++j) {
                hi[j] = f2bf_rne(fv[j]);
                lo[j] = f2bf_rne(fv[j] - bf2f(hi[j]));
            }
            uint4 w;
            unsigned char* cp = Bb + bcol * 128;
            const int m7 = bcol & 7;
            w.x = (unsigned)hi[0] | ((unsigned)hi[1] << 16);
            w.y = (unsigned)hi[2] | ((unsigned)hi[3] << 16);
            w.z = (unsigned)hi[4] | ((unsigned)hi[5] << 16);
            w.w = (unsigned)hi[6] | ((unsigned)hi[7] << 16);
            *reinterpret_cast<uint4*>(cp + (((bks * 2 + 0) ^ m7) << 4)) = w;
            w.x = (unsigned)hi[8]  | ((unsigned)hi[9]  << 16);
            w.y = (unsigned)hi[10] | ((unsigned)hi[11] << 16);
            w.z = (unsigned)hi[12] | ((unsigned)hi[13] << 16);
            w.w = (unsigned)hi[14] | ((unsigned)hi[15] << 16);
            *reinterpret_cast<uint4*>(cp + (((bks * 2 + 1) ^ m7) << 4)) = w;
            w.x = (unsigned)lo[0] | ((unsigned)lo[1] << 16);
            w.y = (unsigned)lo[2] | ((unsigned)lo[3] << 16);
            w.z = (unsigned)lo[4] | ((unsigned)lo[5] << 16);
            w.w = (unsigned)lo[6] | ((unsigned)lo[7] << 16);
            *reinterpret_cast<uint4*>(cp + (((bks * 2 + 4) ^ m7) << 4)) = w;
            w.x = (unsigned)lo[8]  | ((unsigned)lo[9]  << 16);
            w.y = (unsigned)lo[10] | ((unsigned)lo[11] << 16);
            w.z = (unsigned)lo[12] | ((unsigned)lo[13] << 16);
            w.w = (unsigned)lo[14] | ((unsigned)lo[15] << 16);
            *reinterpret_cast<uint4*>(cp + (((bks * 2 + 5) ^ m7) << 4)) = w;
        }
        __syncthreads();
        bf16x8 ah[4], al[4], bh[4], bl[4];
        #pragma unroll
        for (int f = 0; f < 4; ++f) {
            const int R = wm * 64 + f * 16 + l15;
            const unsigned char* rp = Ab + R * 128;
            const int m7 = R & 7;
            ah[f] = *reinterpret_cast<const bf16x8*>(rp + ((lg ^ m7) << 4));
            al[f] = *reinterpret_cast<const bf16x8*>(rp + (((lg + 4) ^ m7) << 4));
            const int Cc = wn * 64 + f * 16 + l15;
            const unsigned char* cp = Bb + Cc * 128;
            const int c7 = Cc & 7;
            bh[f] = *reinterpret_cast<const bf16x8*>(cp + ((lg ^ c7) << 4));
            bl[f] = *reinterpret_cast<const bf16x8*>(cp + (((lg + 4) ^ c7) << 4));
        }
        __syncthreads();
        #pragma unroll
        for (int mf = 0; mf < 4; ++mf)
            #pragma unroll
            for (int nf = 0; nf < 4; ++nf) {
                acc[mf][nf] = __builtin_amdgcn_mfma_f32_16x16x32_bf16(
                    ah[mf], bh[nf], acc[mf][nf], 0, 0, 0);
                acc[mf][nf] = __builtin_amdgcn_mfma_f32_16x16x32_bf16(
                    al[mf], bh[nf], acc[mf][nf], 0, 0, 0);
                acc[mf][nf] = __builtin_amdgcn_mfma_f32_16x16x32_bf16(
                    ah[mf], bl[nf], acc[mf][nf], 0, 0, 0);
            }
    }
    #pragma unroll
    for (int mf = 0; mf < 4; ++mf) {
        #pragma unroll
        for (int nf = 0; nf < 4; ++nf) {
            const int col = bx + wn * 64 + nf * 16 + l15;
            #pragma unroll
            for (int r = 0; r < 4; ++r) {
                const int row = by + wm * 64 + mf * 16 + lg * 4 + r;
                C[(size_t)row * N + col] = acc[mf][nf][r];
            }
        }
    }
}

// ---------------------------------------------------------------------------
// f64-accumulation GEMM for decision path (K,V). 64x64 tile, BK=16.
// ---------------------------------------------------------------------------
__global__ __launch_bounds__(256) void gemm_f64acc(const float* __restrict__ A,
                                                   const float* __restrict__ B,
                                                   double* __restrict__ C,
                                                   int M, int N, int K) {
    const int BM = 64, BN = 64, BK = 16;
    __shared__ double As[BK][BM + 2];
    __shared__ double Bs[BK][BN + 2];
    const int tid = threadIdx.x;
    const int tx = tid & 15, ty = tid >> 4;
    const int bx = blockIdx.x * BN, by = blockIdx.y * BM;

    double acc[4][4] = {};

    for (int k0 = 0; k0 < K; k0 += BK) {
        #pragma unroll
        for (int i = 0; i < 4; ++i) {
            int idx = tid + i * 256;
            int ar = idx >> 4, ac = idx & 15;
            As[ac][ar] = (double)A[(size_t)(by + ar) * K + k0 + ac];
            int br = idx >> 6, bc = idx & 63;
            Bs[br][bc] = (double)B[(size_t)(k0 + br) * N + bx + bc];
        }
        __syncthreads();
        #pragma unroll
        for (int kk = 0; kk < BK; ++kk) {
            double av[4], bv[4];
            #pragma unroll
            for (int i = 0; i < 4; ++i) { av[i] = As[kk][ty * 4 + i]; bv[i] = Bs[kk][tx * 4 + i]; }
            #pragma unroll
            for (int i = 0; i < 4; ++i)
                #pragma unroll
                for (int j = 0; j < 4; ++j)
                    acc[i][j] = fma(av[i], bv[j], acc[i][j]);
        }
        __syncthreads();
    }
    #pragma unroll
    for (int i = 0; i < 4; ++i)
        #pragma unroll
        for (int j = 0; j < 4; ++j)
            C[(size_t)(by + ty * 4 + i) * N + bx + tx * 4 + j] = acc[i][j];
}

// ---------------------------------------------------------------------------
// RoPE: q (f32, in place) and kD (f64, in place).
// ---------------------------------------------------------------------------
__global__ __launch_bounds__(256) void rope_q(float* __restrict__ q,
                                              const float* __restrict__ cosT,
                                              const float* __restrict__ sinT) {
    int idx = blockIdx.x * 256 + threadIdx.x;
    int t = idx / (NH * 64);
    int rem = idx % (NH * 64);
    int h = rem >> 6, d = rem & 63;
    float c1 = cosT[t * DH + d], s1 = sinT[t * DH + d];
    float c2 = cosT[t * DH + d + 64], s2 = sinT[t * DH + d + 64];
    float* base = q + (size_t)t * HID + h * DH;
    float x1 = base[d], x2 = base[d + 64];
    base[d]      = x1 * c1 - x2 * s1;
    base[d + 64] = x2 * c2 + x1 * s2;
}

__global__ __launch_bounds__(256) void rope_kD(double* __restrict__ kD,
                                               const float* __restrict__ cosT,
                                               const float* __restrict__ sinT) {
    int idx = blockIdx.x * 256 + threadIdx.x;
    int t = idx / (NKVH * 64);
    int rem = idx % (NKVH * 64);
    int h = rem >> 6, d = rem & 63;
    double c1 = (double)cosT[t * DH + d], s1 = (double)sinT[t * DH + d];
    double c2 = (double)cosT[t * DH + d + 64], s2 = (double)sinT[t * DH + d + 64];
    double* base = kD + ((size_t)t * NKVH + h) * DH;
    double x1 = base[d], x2 = base[d + 64];
    base[d]      = x1 * c1 - x2 * s1;
    base[d + 64] = x2 * c2 + x1 * s2;
}

// ---------------------------------------------------------------------------
// qlastD[20][HID] = hs[last 20 rows] @ Wq, f64 accumulation, Wq read ONCE.
// Grid: 64 blocks (64 cols each); per-thread 5 rows x 1 col; k-order 0..HID-1
// (same accumulation order as the old imp_head -> identical rounding).
// ---------------------------------------------------------------------------
__global__ __launch_bounds__(256) void qlast_f64(const float* __restrict__ hs,
                                                 const float* __restrict__ Wq,
                                                 double* __restrict__ qlastD) {
    __shared__ float hsC[LAST][128];     // 10 KiB
    __shared__ float WqC[128][65];       // 33.3 KiB
    const int tid = threadIdx.x;
    const int n0 = blockIdx.x * 64;
    const int nc = tid & 63;
    const int jg = tid >> 6;             // 0..3 -> rows jg*5..jg*5+4
    double acc[5] = {};

    for (int k0 = 0; k0 < HID; k0 += 128) {
        for (int e = tid; e < LAST * 128; e += 256) {
            int j = e >> 7, kk = e & 127;
            hsC[j][kk] = hs[(size_t)(S - LAST + j) * HID + k0 + kk];
        }
        for (int e = tid; e < 128 * 64; e += 256) {
            int r = e >> 6, c = e & 63;
            WqC[r][c] = Wq[(size_t)(k0 + r) * HID + n0 + c];
        }
        __syncthreads();
        #pragma unroll 4
        for (int kk = 0; kk < 128; ++kk) {
            double w = (double)WqC[kk][nc];
            #pragma unroll
            for (int jj = 0; jj < 5; ++jj)
                acc[jj] = fma((double)hsC[jg * 5 + jj][kk], w, acc[jj]);
        }
        __syncthreads();
    }
    #pragma unroll
    for (int jj = 0; jj < 5; ++jj)
        qlastD[(size_t)(jg * 5 + jj) * HID + n0 + nc] = acc[jj];
}

// RoPE on qlastD (f64), 20*NH*64 elements.
__global__ __launch_bounds__(256) void rope_qlastD(double* __restrict__ qD,
                                                   const float* __restrict__ cosT,
                                                   const float* __restrict__ sinT) {
    int idx = blockIdx.x * 256 + threadIdx.x;    // 20*32*64 = 40960
    if (idx >= LAST * NH * 64) return;
    int j = idx / (NH * 64);
    int rem = idx % (NH * 64);
    int h = rem >> 6, d = rem & 63;
    int t = S - LAST + j;
    double c1 = (double)cosT[t * DH + d], s1 = (double)sinT[t * DH + d];
    double c2 = (double)cosT[t * DH + d + 64], s2 = (double)sinT[t * DH + d + 64];
    double* base = qD + (size_t)j * HID + h * DH;
    double x1 = base[d], x2 = base[d + 64];
    base[d]      = x1 * c1 - x2 * s1;
    base[d + 64] = x2 * c2 + x1 * s2;
}

// ---------------------------------------------------------------------------
// Importance scores f64: one block per (h,j). Row softmax -> awD row.
// ---------------------------------------------------------------------------
__global__ __launch_bounds__(256) void imp_scores64(const double* __restrict__ qlastD,
                                                    const double* __restrict__ kD,
                                                    double* __restrict__ awD) {
    const double SC = 0.08838834764831843;   // 128^-0.5
    const int h = blockIdx.x, j = blockIdx.y;
    const int qpos = S - LAST + j;
    const int kvh = h >> 2;
    const int tid = threadIdx.x;
    const int lane = tid & 63, wid = tid >> 6;
    __shared__ double qs[DH];
    __shared__ double redA[4], redB[4];
    if (tid < DH) qs[tid] = qlastD[(size_t)j * HID + h * DH + tid];
    __syncthreads();

    double sloc[8];
    int cnt = 0;
    double lmax = -1e300;
    for (int kp = tid; kp <= qpos; kp += 256) {
        const double* kr = kD + ((size_t)kp * NKVH + kvh) * DH;
        double s = 0.0;
        #pragma unroll 8
        for (int d = 0; d < DH; ++d) s = fma(qs[d], kr[d], s);
        s *= SC;
        sloc[cnt++] = s;
        lmax = fmax(lmax, s);
    }
    #pragma unroll
    for (int o = 32; o > 0; o >>= 1) lmax = fmax(lmax, __shfl_xor(lmax, o));
    if (lane == 0) redA[wid] = lmax;
    __syncthreads();
    double gmax = fmax(fmax(redA[0], redA[1]), fmax(redA[2], redA[3]));
    double lsum = 0.0;
    for (int i = 0; i < cnt; ++i) lsum += exp(sloc[i] - gmax);
    #pragma unroll
    for (int o = 32; o > 0; o >>= 1) lsum += __shfl_xor(lsum, o);
    if (lane == 0) redB[wid] = lsum;
    __syncthreads();
    double inv = 1.0 / (redB[0] + redB[1] + redB[2] + redB[3]);
    double* ar = awD + (size_t)(h * LAST + j) * S;
    int i = 0;
    for (int kp = tid; kp < S; kp += 256) {
        double val = 0.0;
        if (kp <= qpos) { val = exp(sloc[i] - gmax) * inv; ++i; }
        ar[kp] = val;
    }
}

// timpD[kp] = sum_rows(awD[:,kp]) / count  (row order h-major,j-minor = old order)
__global__ __launch_bounds__(256) void imp_finish64(const double* __restrict__ awD,
                                                    double* __restrict__ timpD) {
    int kp = blockIdx.x * 256 + threadIdx.x;
    double s = 0.0;
    for (int r = 0; r < NH * LAST; ++r) s += awD[(size_t)r * S + kp];
    int cntv = (kp >= S - LAST) ? (S - kp) : LAST;
    timpD[kp] = s / (double)cntv;
}

// ---------------------------------------------------------------------------
// Block importance (f64) -> stable descending argsort -> per-token levels.
// ---------------------------------------------------------------------------
__global__ __launch_bounds__(64) void bits_alloc(const double* __restrict__ timpD,
                                                 const float* __restrict__ ratio,
                                                 float* __restrict__ levels_tok) {
    __shared__ double bimp[NBLK];
    __shared__ int bbits[NBLK];
    __shared__ unsigned char taken[NBLK];
    int tid = threadIdx.x;
    double s = 0.0;
    for (int i = 0; i < BLOCK_TOK; ++i) s += timpD[tid * BLOCK_TOK + i];
    bimp[tid] = s;
    taken[tid] = 0;
    __syncthreads();
    if (tid == 0) {
        int kb[4], tot = 0;
        for (int g = 0; g < 4; ++g) { kb[g] = (int)rint(64.0 * (double)ratio[g]); tot += kb[g]; }
        kb[3] += NBLK - tot;
        int c0 = kb[0], c1 = kb[0] + kb[1], c2 = kb[0] + kb[1] + kb[2];
        for (int r = 0; r < NBLK; ++r) {
            int best = -1; double bv = 0.0;
            for (int b2 = 0; b2 < NBLK; ++b2) {
                if (!taken[b2] && (best < 0 || bimp[b2] > bv)) { bv = bimp[b2]; best = b2; }
            }
            taken[best] = 1;
            int g = (r >= c0) + (r >= c1) + (r >= c2);  // searchsorted 'right'
            bbits[best] = 8 >> g;                        // BITS = {8,4,2,1}
        }
    }
    __syncthreads();
    float lev = (float)((1 << bbits[tid]) - 1);
    for (int i = 0; i < BLOCK_TOK; ++i) levels_tok[tid * BLOCK_TOK + i] = lev;
}

// ---------------------------------------------------------------------------
// Fake quant in f64, narrowing in place (f64 row -> f32 at row base).
// ---------------------------------------------------------------------------
__global__ __launch_bounds__(64) void fakequant(double* __restrict__ kD,
                                                double* __restrict__ vD,
                                                const float* __restrict__ levels_tok) {
    int row = blockIdx.x;
    double lev = (double)levels_tok[row >> 3];
    int lane = threadIdx.x;
    #pragma unroll
    for (int which = 0; which < 2; ++which) {
        double* p = (which ? vD : kD) + (size_t)row * DH;
        double x0 = p[lane], x1 = p[lane + 64];
        double mn = fmin(x0, x1), mx = fmax(x0, x1);
        #pragma unroll
        for (int o = 1; o < 64; o <<= 1) {
            mn = fmin(mn, __shfl_xor(mn, o));
            mx = fmax(mx, __shfl_xor(mx, o));
        }
        double scale = fmax((mx - mn) / lev, 1e-8);
        double q0 = rint((x0 - mn) / scale) * scale + mn;
        double q1 = rint((x1 - mn) / scale) * scale + mn;
        __syncthreads();
        float* f = (float*)p;
        f[lane]      = (float)q0;
        f[lane + 64] = (float)q1;
        __syncthreads();
    }
}

// ---------------------------------------------------------------------------
// Flash attention over quantized KV (f32 views, row stride 256 floats).
// ctx written IN PLACE over q.
// ---------------------------------------------------------------------------
__global__ __launch_bounds__(256) void attn_flash(float* __restrict__ q,
                                                  const float* __restrict__ kf,
                                                  const float* __restrict__ vf) {
    const float SCALING = 0.08838834764831843f;
    const int h = blockIdx.x;
    const int qt = blockIdx.y;
    const int q0 = qt * QB;
    const int kvh = h >> 2;
    __shared__ float Qs[QB][DH + 4];
    __shared__ float Ks[QB][DH + 4];
    __shared__ float Vs[QB][DH + 4];
    __shared__ float Ps[QB][QB + 1];
    const int tid = threadIdx.x;
    const int tq = tid >> 4;
    const int tg = tid & 15;

    {
        int r = tid >> 3, c = (tid & 7) * 16;
        const float* src = &q[(size_t)(q0 + r) * HID + h * DH + c];
        #pragma unroll
        for (int j = 0; j < 4; ++j)
            *reinterpret_cast<float4*>(&Qs[r][c + 4 * j]) =
                *reinterpret_cast<const float4*>(&src[4 * j]);
    }
    float m0 = -INFINITY, m1 = -INFINITY, l0 = 0.f, l1 = 0.f;
    float acc0[8] = {}, acc1[8] = {};
    __syncthreads();

    for (int kt = 0; kt <= qt; ++kt) {
        const int kbase = kt * QB;
        {
            int r = tid >> 3, c = (tid & 7) * 16;
            const float* ksrc = kf + ((((size_t)(kbase + r)) * NKVH + kvh) << 8) + c;
            const float* vsrc = vf + ((((size_t)(kbase + r)) * NKVH + kvh) << 8) + c;
            #pragma unroll
            for (int j = 0; j < 4; ++j) {
                *reinterpret_cast<float4*>(&Ks[r][c + 4 * j]) =
                    *reinterpret_cast<const float4*>(&ksrc[4 * j]);
                *reinterpret_cast<float4*>(&Vs[r][c + 4 * j]) =
                    *reinterpret_cast<const float4*>(&vsrc[4 * j]);
            }
        }
        __syncthreads();

        float s00 = 0.f, s01 = 0.f, s10 = 0.f, s11 = 0.f;
        #pragma unroll 8
        for (int dc = 0; dc < DH; dc += 4) {
            float4 qa = *reinterpret_cast<const float4*>(&Qs[tq][dc]);
            float4 qb = *reinterpret_cast<const float4*>(&Qs[tq + 16][dc]);
            float4 ka = *reinterpret_cast<const float4*>(&Ks[tg][dc]);
            float4 kb = *reinterpret_cast<const float4*>(&Ks[tg + 16][dc]);
            s00 += qa.x * ka.x + qa.y * ka.y + qa.z * ka.z + qa.w * ka.w;
            s01 += qa.x * kb.x + qa.y * kb.y + qa.z * kb.z + qa.w * kb.w;
            s10 += qb.x * ka.x + qb.y * ka.y + qb.z * ka.z + qb.w * ka.w;
            s11 += qb.x * kb.x + qb.y * kb.y + qb.z * kb.z + qb.w * kb.w;
        }
        s00 *= SCALING; s01 *= SCALING; s10 *= SCALING; s11 *= SCALING;
        const int qg0 = q0 + tq, qg1 = q0 + tq + 16;
        const int k0g = kbase + tg, k1g = kbase + tg + 16;
        if (k0g > qg0) s00 = -INFINITY;
        if (k1g > qg0) s01 = -INFINITY;
        if (k0g > qg1) s10 = -INFINITY;
        if (k1g > qg1) s11 = -INFINITY;

        float t0 = fmaxf(s00, s01), t1 = fmaxf(s10, s11);
        #pragma unroll
        for (int o = 1; o < 16; o <<= 1) {
            t0 = fmaxf(t0, __shfl_xor(t0, o));
            t1 = fmaxf(t1, __shfl_xor(t1, o));
        }
        float mn0 = fmaxf(m0, t0), mn1 = fmaxf(m1, t1);
        float c0 = expf(m0 - mn0), c1 = expf(m1 - mn1);
        float p00 = expf(s00 - mn0), p01 = expf(s01 - mn0);
        float p10 = expf(s10 - mn1), p11 = expf(s11 - mn1);
        float u0 = p00 + p01, u1 = p10 + p11;
        #pragma unroll
        for (int o = 1; o < 16; o <<= 1) {
            u0 += __shfl_xor(u0, o);
            u1 += __shfl_xor(u1, o);
        }
        l0 = l0 * c0 + u0; l1 = l1 * c1 + u1;
        m0 = mn0; m1 = mn1;
        Ps[tq][tg] = p00;      Ps[tq][tg + 16] = p01;
        Ps[tq + 16][tg] = p10; Ps[tq + 16][tg + 16] = p11;
        #pragma unroll
        for (int j = 0; j < 8; ++j) { acc0[j] *= c0; acc1[j] *= c1; }
        __syncthreads();

        #pragma unroll 4
        for (int kk = 0; kk < QB; ++kk) {
            float p0 = Ps[tq][kk], p1 = Ps[tq + 16][kk];
            float4 v0 = *reinterpret_cast<const float4*>(&Vs[kk][tg * 4]);
            float4 v1 = *reinterpret_cast<const float4*>(&Vs[kk][64 + tg * 4]);
            acc0[0] = fmaf(p0, v0.x, acc0[0]); acc0[1] = fmaf(p0, v0.y, acc0[1]);
            acc0[2] = fmaf(p0, v0.z, acc0[2]); acc0[3] = fmaf(p0, v0.w, acc0[3]);
            acc0[4] = fmaf(p0, v1.x, acc0[4]); acc0[5] = fmaf(p0, v1.y, acc0[5]);
            acc0[6] = fmaf(p0, v1.z, acc0[6]); acc0[7] = fmaf(p0, v1.w, acc0[7]);
            acc1[0] = fmaf(p1, v0.x, acc1[0]); acc1[1] = fmaf(p1, v0.y, acc1[1]);
            acc1[2] = fmaf(p1, v0.z, acc1[2]); acc1[3] = fmaf(p1, v0.w, acc1[3]);
            acc1[4] = fmaf(p1, v1.x, acc1[4]); acc1[5] = fmaf(p1, v1.y, acc1[5]);
            acc1[6] = fmaf(p1, v1.z, acc1[6]); acc1[7] = fmaf(p1, v1.w, acc1[7]);
        }
        __syncthreads();
    }

    float i0 = 1.0f / l0, i1 = 1.0f / l1;
    float* o0 = &q[(size_t)(q0 + tq) * HID + h * DH];
    float* o1 = &q[(size_t)(q0 + tq + 16) * HID + h * DH];
    float4 w;
    w = make_float4(acc0[0] * i0, acc0[1] * i0, acc0[2] * i0, acc0[3] * i0);
    *reinterpret_cast<float4*>(&o0[tg * 4]) = w;
    w = make_float4(acc0[4] * i0, acc0[5] * i0, acc0[6] * i0, acc0[7] * i0);
    *reinterpret_cast<float4*>(&o0[64 + tg * 4]) = w;
    w = make_float4(acc1[0] * i1, acc1[1] * i1, acc1[2] * i1, acc1[3] * i1);
    *reinterpret_cast<float4*>(&o1[tg * 4]) = w;
    w = make_float4(acc1[4] * i1, acc1[5] * i1, acc1[6] * i1, acc1[7] * i1);
    *reinterpret_cast<float4*>(&o1[64 + tg * 4]) = w;
}

// ---------------------------------------------------------------------------
extern "C" void kernel_launch(void* const* d_in, const int* in_sizes, int n_in,
                              void* d_out, int out_size, void* d_ws, size_t ws_size,
                              hipStream_t stream) {
    const float* hs    = (const float*)d_in[0];
    const float* cosT  = (const float*)d_in[1];
    const float* sinT  = (const float*)d_in[2];
    /* d_in[3] attention_mask: pure causal, reconstructed analytically */
    const float* ratio = (const float*)d_in[4];
    const float* Wq    = (const float*)d_in[5];
    const float* Wk    = (const float*)d_in[6];
    const float* Wv    = (const float*)d_in[7];
    const float* Wo    = (const float*)d_in[8];
    float* out = (float*)d_out;

    // ws layout (~78 MB): f64 buffers first, then f32.
    double* kD     = (double*)d_ws;                      // S*NKVH*DH  f64
    double* vD     = kD + (size_t)S * NKVH * DH;         // S*NKVH*DH  f64
    double* qlastD = vD + (size_t)S * NKVH * DH;         // LAST*HID   f64
    double* awD    = qlastD + (size_t)LAST * HID;        // NH*LAST*S  f64
    double* timpD  = awD + (size_t)NH * LAST * S;        // S          f64
    float*  qbuf   = (float*)(timpD + S);                // S*HID      f32
    float*  levels = qbuf + (size_t)S * HID;             // S          f32

    dim3 blk(256);
    gemm_split<<<dim3(HID / 128, S / 128), blk, 0, stream>>>(hs, Wq, qbuf, S, HID, HID);
    gemm_f64acc<<<dim3((NKVH * DH) / 64, S / 64), blk, 0, stream>>>(hs, Wk, kD, S, NKVH * DH, HID);
    gemm_f64acc<<<dim3((NKVH * DH) / 64, S / 64), blk, 0, stream>>>(hs, Wv, vD, S, NKVH * DH, HID);

    rope_q<<<(S * NH * 64) / 256, blk, 0, stream>>>(qbuf, cosT, sinT);
    rope_kD<<<(S * NKVH * 64) / 256, blk, 0, stream>>>(kD, cosT, sinT);

    qlast_f64<<<HID / 64, blk, 0, stream>>>(hs, Wq, qlastD);
    rope_qlastD<<<(LAST * NH * 64 + 255) / 256, blk, 0, stream>>>(qlastD, cosT, sinT);
    imp_scores64<<<dim3(NH, LAST), blk, 0, stream>>>(qlastD, kD, awD);
    imp_finish64<<<S / 256, blk, 0, stream>>>(awD, timpD);
    bits_alloc<<<1, 64, 0, stream>>>(timpD, ratio, levels);
    fakequant<<<S * NKVH, 64, 0, stream>>>(kD, vD, levels);

    attn_flash<<<dim3(NH, S / QB), blk, 0, stream>>>(qbuf, (const float*)kD, (const float*)vD);

    gemm_split<<<dim3(HID / 128, S / 128), blk, 0, stream>>>(qbuf, Wo, out, S, HID, HID);
}

// Round 12
// 2703.853 us; speedup vs baseline: 2.2994x; 1.1924x over previous
//
#include <hip/hip_runtime.h>
#include <hip/hip_bf16.h>
#include <cmath>

#define S 2048
#define HID 4096
#define NH 32
#define NKVH 8
#define DH 128
#define LAST 20
#define BLOCK_TOK 32
#define NBLK 64  /* S / BLOCK_TOK */
#define QB 32    /* flash q-tile */

typedef __attribute__((ext_vector_type(8))) short bf16x8;
typedef __attribute__((ext_vector_type(4))) float f32x4;
typedef unsigned short u16;

static __device__ __forceinline__ u16 f2bf_rne(float x) {
    unsigned int u = __float_as_uint(x);
    unsigned int r = (u + 0x7FFFu + ((u >> 16) & 1u)) >> 16;
    return (u16)r;
}
static __device__ __forceinline__ float bf2f(u16 h) {
    return __uint_as_float(((unsigned int)h) << 16);
}

// ---------------------------------------------------------------------------
// Split-bf16 MFMA GEMM (post-decision paths: Q-proj, O-proj). VALIDATED r6-r8.
// ---------------------------------------------------------------------------
__global__ __launch_bounds__(256) void gemm_split(const float* __restrict__ A,
                                                  const float* __restrict__ B,
                                                  float* __restrict__ C,
                                                  int M, int N, int K) {
    __shared__ __align__(16) unsigned char smem[32768];
    unsigned char* Ab = smem;
    unsigned char* Bb = smem + 16384;
    const int tid = threadIdx.x;
    const int bx = blockIdx.x * 128;
    const int by = blockIdx.y * 128;
    const int lane = tid & 63, wid = tid >> 6;
    const int wm = wid >> 1, wn = wid & 1;
    const int l15 = lane & 15, lg = lane >> 4;

    const int ar = tid >> 1, akh = tid & 1;
    const int bcol = tid & 127, bks = tid >> 7;

    f32x4 acc[4][4];
    #pragma unroll
    for (int i = 0; i < 4; ++i)
        #pragma unroll
        for (int j = 0; j < 4; ++j)
            acc[i][j] = (f32x4){0.f, 0.f, 0.f, 0.f};

    for (int k0 = 0; k0 < K; k0 += 32) {
        {
            const float* ap = A + (size_t)(by + ar) * K + k0 + akh * 16;
            float fv[16];
            #pragma unroll
            for (int j = 0; j < 4; ++j) {
                float4 t4 = *reinterpret_cast<const float4*>(ap + 4 * j);
                fv[4 * j + 0] = t4.x; fv[4 * j + 1] = t4.y;
                fv[4 * j + 2] = t4.z; fv[4 * j + 3] = t4.w;
            }
            u16 hi[16], lo[16];
            #pragma unroll
            for (int j = 0; j < 16; ++j) {
                hi[j] = f2bf_rne(fv[j]);
                lo[j] = f2bf_rne(fv[j] - bf2f(hi[j]));
            }
            uint4 w;
            unsigned char* rp = Ab + ar * 128;
            const int m7 = ar & 7;
            w.x = (unsigned)hi[0] | ((unsigned)hi[1] << 16);
            w.y = (unsigned)hi[2] | ((unsigned)hi[3] << 16);
            w.z = (unsigned)hi[4] | ((unsigned)hi[5] << 16);
            w.w = (unsigned)hi[6] | ((unsigned)hi[7] << 16);
            *reinterpret_cast<uint4*>(rp + (((akh * 2 + 0) ^ m7) << 4)) = w;
            w.x = (unsigned)hi[8]  | ((unsigned)hi[9]  << 16);
            w.y = (unsigned)hi[10] | ((unsigned)hi[11] << 16);
            w.z = (unsigned)hi[12] | ((unsigned)hi[13] << 16);
            w.w = (unsigned)hi[14] | ((unsigned)hi[15] << 16);
            *reinterpret_cast<uint4*>(rp + (((akh * 2 + 1) ^ m7) << 4)) = w;
            w.x = (unsigned)lo[0] | ((unsigned)lo[1] << 16);
            w.y = (unsigned)lo[2] | ((unsigned)lo[3] << 16);
            w.z = (unsigned)lo[4] | ((unsigned)lo[5] << 16);
            w.w = (unsigned)lo[6] | ((unsigned)lo[7] << 16);
            *reinterpret_cast<uint4*>(rp + (((akh * 2 + 4) ^ m7) << 4)) = w;
            w.x = (unsigned)lo[8]  | ((unsigned)lo[9]  << 16);
            w.y = (unsigned)lo[10] | ((unsigned)lo[11] << 16);
            w.z = (unsigned)lo[12] | ((unsigned)lo[13] << 16);
            w.w = (unsigned)lo[14] | ((unsigned)lo[15] << 16);
            *reinterpret_cast<uint4*>(rp + (((akh * 2 + 5) ^ m7) << 4)) = w;
        }
        {
            const float* bp = B + (size_t)(k0 + bks * 16) * N + bx + bcol;
            float fv[16];
            #pragma unroll
            for (int j = 0; j < 16; ++j) fv[j] = bp[(size_t)j * N];
            u16 hi[16], lo[16];
            #pragma unroll
            for (int j = 0; j < 16; ++j) {
                hi[j] = f2bf_rne(fv[j]);
                lo[j] = f2bf_rne(fv[j] - bf2f(hi[j]));
            }
            uint4 w;
            unsigned char* cp = Bb + bcol * 128;
            const int m7 = bcol & 7;
            w.x = (unsigned)hi[0] | ((unsigned)hi[1] << 16);
            w.y = (unsigned)hi[2] | ((unsigned)hi[3] << 16);
            w.z = (unsigned)hi[4] | ((unsigned)hi[5] << 16);
            w.w = (unsigned)hi[6] | ((unsigned)hi[7] << 16);
            *reinterpret_cast<uint4*>(cp + (((bks * 2 + 0) ^ m7) << 4)) = w;
            w.x = (unsigned)hi[8]  | ((unsigned)hi[9]  << 16);
            w.y = (unsigned)hi[10] | ((unsigned)hi[11] << 16);
            w.z = (unsigned)hi[12] | ((unsigned)hi[13] << 16);
            w.w = (unsigned)hi[14] | ((unsigned)hi[15] << 16);
            *reinterpret_cast<uint4*>(cp + (((bks * 2 + 1) ^ m7) << 4)) = w;
            w.x = (unsigned)lo[0] | ((unsigned)lo[1] << 16);
            w.y = (unsigned)lo[2] | ((unsigned)lo[3] << 16);
            w.z = (unsigned)lo[4] | ((unsigned)lo[5] << 16);
            w.w = (unsigned)lo[6] | ((unsigned)lo[7] << 16);
            *reinterpret_cast<uint4*>(cp + (((bks * 2 + 4) ^ m7) << 4)) = w;
            w.x = (unsigned)lo[8]  | ((unsigned)lo[9]  << 16);
            w.y = (unsigned)lo[10] | ((unsigned)lo[11] << 16);
            w.z = (unsigned)lo[12] | ((unsigned)lo[13] << 16);
            w.w = (unsigned)lo[14] | ((unsigned)lo[15] << 16);
            *reinterpret_cast<uint4*>(cp + (((bks * 2 + 5) ^ m7) << 4)) = w;
        }
        __syncthreads();
        bf16x8 ah[4], al[4], bh[4], bl[4];
        #pragma unroll
        for (int f = 0; f < 4; ++f) {
            const int R = wm * 64 + f * 16 + l15;
            const unsigned char* rp = Ab + R * 128;
            const int m7 = R & 7;
            ah[f] = *reinterpret_cast<const bf16x8*>(rp + ((lg ^ m7) << 4));
            al[f] = *reinterpret_cast<const bf16x8*>(rp + (((lg + 4) ^ m7) << 4));
            const int Cc = wn * 64 + f * 16 + l15;
            const unsigned char* cp = Bb + Cc * 128;
            const int c7 = Cc & 7;
            bh[f] = *reinterpret_cast<const bf16x8*>(cp + ((lg ^ c7) << 4));
            bl[f] = *reinterpret_cast<const bf16x8*>(cp + (((lg + 4) ^ c7) << 4));
        }
        __syncthreads();
        #pragma unroll
        for (int mf = 0; mf < 4; ++mf)
            #pragma unroll
            for (int nf = 0; nf < 4; ++nf) {
                acc[mf][nf] = __builtin_amdgcn_mfma_f32_16x16x32_bf16(
                    ah[mf], bh[nf], acc[mf][nf], 0, 0, 0);
                acc[mf][nf] = __builtin_amdgcn_mfma_f32_16x16x32_bf16(
                    al[mf], bh[nf], acc[mf][nf], 0, 0, 0);
                acc[mf][nf] = __builtin_amdgcn_mfma_f32_16x16x32_bf16(
                    ah[mf], bl[nf], acc[mf][nf], 0, 0, 0);
            }
    }
    #pragma unroll
    for (int mf = 0; mf < 4; ++mf) {
        #pragma unroll
        for (int nf = 0; nf < 4; ++nf) {
            const int col = bx + wn * 64 + nf * 16 + l15;
            #pragma unroll
            for (int r = 0; r < 4; ++r) {
                const int row = by + wm * 64 + mf * 16 + lg * 4 + r;
                C[(size_t)row * N + col] = acc[mf][nf][r];
            }
        }
    }
}

// ---------------------------------------------------------------------------
// f64-accumulation GEMM for decision path (K,V). 64x64 tile, BK=16.
// ---------------------------------------------------------------------------
__global__ __launch_bounds__(256) void gemm_f64acc(const float* __restrict__ A,
                                                   const float* __restrict__ B,
                                                   double* __restrict__ C,
                                                   int M, int N, int K) {
    const int BM = 64, BN = 64, BK = 16;
    __shared__ double As[BK][BM + 2];
    __shared__ double Bs[BK][BN + 2];
    const int tid = threadIdx.x;
    const int tx = tid & 15, ty = tid >> 4;
    const int bx = blockIdx.x * BN, by = blockIdx.y * BM;

    double acc[4][4] = {};

    for (int k0 = 0; k0 < K; k0 += BK) {
        #pragma unroll
        for (int i = 0; i < 4; ++i) {
            int idx = tid + i * 256;
            int ar = idx >> 4, ac = idx & 15;
            As[ac][ar] = (double)A[(size_t)(by + ar) * K + k0 + ac];
            int br = idx >> 6, bc = idx & 63;
            Bs[br][bc] = (double)B[(size_t)(k0 + br) * N + bx + bc];
        }
        __syncthreads();
        #pragma unroll
        for (int kk = 0; kk < BK; ++kk) {
            double av[4], bv[4];
            #pragma unroll
            for (int i = 0; i < 4; ++i) { av[i] = As[kk][ty * 4 + i]; bv[i] = Bs[kk][tx * 4 + i]; }
            #pragma unroll
            for (int i = 0; i < 4; ++i)
                #pragma unroll
                for (int j = 0; j < 4; ++j)
                    acc[i][j] = fma(av[i], bv[j], acc[i][j]);
        }
        __syncthreads();
    }
    #pragma unroll
    for (int i = 0; i < 4; ++i)
        #pragma unroll
        for (int j = 0; j < 4; ++j)
            C[(size_t)(by + ty * 4 + i) * N + bx + tx * 4 + j] = acc[i][j];
}

// ---------------------------------------------------------------------------
// RoPE: q (f32, in place) and kD (f64, in place).
// ---------------------------------------------------------------------------
__global__ __launch_bounds__(256) void rope_q(float* __restrict__ q,
                                              const float* __restrict__ cosT,
                                              const float* __restrict__ sinT) {
    int idx = blockIdx.x * 256 + threadIdx.x;
    int t = idx / (NH * 64);
    int rem = idx % (NH * 64);
    int h = rem >> 6, d = rem & 63;
    float c1 = cosT[t * DH + d], s1 = sinT[t * DH + d];
    float c2 = cosT[t * DH + d + 64], s2 = sinT[t * DH + d + 64];
    float* base = q + (size_t)t * HID + h * DH;
    float x1 = base[d], x2 = base[d + 64];
    base[d]      = x1 * c1 - x2 * s1;
    base[d + 64] = x2 * c2 + x1 * s2;
}

__global__ __launch_bounds__(256) void rope_kD(double* __restrict__ kD,
                                               const float* __restrict__ cosT,
                                               const float* __restrict__ sinT) {
    int idx = blockIdx.x * 256 + threadIdx.x;
    int t = idx / (NKVH * 64);
    int rem = idx % (NKVH * 64);
    int h = rem >> 6, d = rem & 63;
    double c1 = (double)cosT[t * DH + d], s1 = (double)sinT[t * DH + d];
    double c2 = (double)cosT[t * DH + d + 64], s2 = (double)sinT[t * DH + d + 64];
    double* base = kD + ((size_t)t * NKVH + h) * DH;
    double x1 = base[d], x2 = base[d + 64];
    base[d]      = x1 * c1 - x2 * s1;
    base[d + 64] = x2 * c2 + x1 * s2;
}

// ---------------------------------------------------------------------------
// qlastD = hs[last 20] @ Wq (f64 acc, Wq read once).
// ---------------------------------------------------------------------------
__global__ __launch_bounds__(256) void qlast_f64(const float* __restrict__ hs,
                                                 const float* __restrict__ Wq,
                                                 double* __restrict__ qlastD) {
    __shared__ float hsC[LAST][128];
    __shared__ float WqC[128][65];
    const int tid = threadIdx.x;
    const int n0 = blockIdx.x * 64;
    const int nc = tid & 63;
    const int jg = tid >> 6;
    double acc[5] = {};

    for (int k0 = 0; k0 < HID; k0 += 128) {
        for (int e = tid; e < LAST * 128; e += 256) {
            int j = e >> 7, kk = e & 127;
            hsC[j][kk] = hs[(size_t)(S - LAST + j) * HID + k0 + kk];
        }
        for (int e = tid; e < 128 * 64; e += 256) {
            int r = e >> 6, c = e & 63;
            WqC[r][c] = Wq[(size_t)(k0 + r) * HID + n0 + c];
        }
        __syncthreads();
        #pragma unroll 4
        for (int kk = 0; kk < 128; ++kk) {
            double w = (double)WqC[kk][nc];
            #pragma unroll
            for (int jj = 0; jj < 5; ++jj)
                acc[jj] = fma((double)hsC[jg * 5 + jj][kk], w, acc[jj]);
        }
        __syncthreads();
    }
    #pragma unroll
    for (int jj = 0; jj < 5; ++jj)
        qlastD[(size_t)(jg * 5 + jj) * HID + n0 + nc] = acc[jj];
}

__global__ __launch_bounds__(256) void rope_qlastD(double* __restrict__ qD,
                                                   const float* __restrict__ cosT,
                                                   const float* __restrict__ sinT) {
    int idx = blockIdx.x * 256 + threadIdx.x;
    if (idx >= LAST * NH * 64) return;
    int j = idx / (NH * 64);
    int rem = idx % (NH * 64);
    int h = rem >> 6, d = rem & 63;
    int t = S - LAST + j;
    double c1 = (double)cosT[t * DH + d], s1 = (double)sinT[t * DH + d];
    double c2 = (double)cosT[t * DH + d + 64], s2 = (double)sinT[t * DH + d + 64];
    double* base = qD + (size_t)j * HID + h * DH;
    double x1 = base[d], x2 = base[d + 64];
    base[d]      = x1 * c1 - x2 * s1;
    base[d + 64] = x2 * c2 + x1 * s2;
}

// ---------------------------------------------------------------------------
// Importance scores f64 (pre-quant kD), then reduce.
// ---------------------------------------------------------------------------
__global__ __launch_bounds__(256) void imp_scores64(const double* __restrict__ qlastD,
                                                    const double* __restrict__ kD,
                                                    double* __restrict__ awD) {
    const double SC = 0.08838834764831843;
    const int h = blockIdx.x, j = blockIdx.y;
    const int qpos = S - LAST + j;
    const int kvh = h >> 2;
    const int tid = threadIdx.x;
    const int lane = tid & 63, wid = tid >> 6;
    __shared__ double qs[DH];
    __shared__ double redA[4], redB[4];
    if (tid < DH) qs[tid] = qlastD[(size_t)j * HID + h * DH + tid];
    __syncthreads();

    double sloc[8];
    int cnt = 0;
    double lmax = -1e300;
    for (int kp = tid; kp <= qpos; kp += 256) {
        const double* kr = kD + ((size_t)kp * NKVH + kvh) * DH;
        double s = 0.0;
        #pragma unroll 8
        for (int d = 0; d < DH; ++d) s = fma(qs[d], kr[d], s);
        s *= SC;
        sloc[cnt++] = s;
        lmax = fmax(lmax, s);
    }
    #pragma unroll
    for (int o = 32; o > 0; o >>= 1) lmax = fmax(lmax, __shfl_xor(lmax, o));
    if (lane == 0) redA[wid] = lmax;
    __syncthreads();
    double gmax = fmax(fmax(redA[0], redA[1]), fmax(redA[2], redA[3]));
    double lsum = 0.0;
    for (int i = 0; i < cnt; ++i) lsum += exp(sloc[i] - gmax);
    #pragma unroll
    for (int o = 32; o > 0; o >>= 1) lsum += __shfl_xor(lsum, o);
    if (lane == 0) redB[wid] = lsum;
    __syncthreads();
    double inv = 1.0 / (redB[0] + redB[1] + redB[2] + redB[3]);
    double* ar = awD + (size_t)(h * LAST + j) * S;
    int i = 0;
    for (int kp = tid; kp < S; kp += 256) {
        double val = 0.0;
        if (kp <= qpos) { val = exp(sloc[i] - gmax) * inv; ++i; }
        ar[kp] = val;
    }
}

__global__ __launch_bounds__(256) void imp_finish64(const double* __restrict__ awD,
                                                    double* __restrict__ timpD) {
    int kp = blockIdx.x * 256 + threadIdx.x;
    double s = 0.0;
    for (int r = 0; r < NH * LAST; ++r) s += awD[(size_t)r * S + kp];
    int cntv = (kp >= S - LAST) ? (S - kp) : LAST;
    timpD[kp] = s / (double)cntv;
}

// ---------------------------------------------------------------------------
// Block importance -> stable argsort -> per-token levels.
// ---------------------------------------------------------------------------
__global__ __launch_bounds__(64) void bits_alloc(const double* __restrict__ timpD,
                                                 const float* __restrict__ ratio,
                                                 float* __restrict__ levels_tok) {
    __shared__ double bimp[NBLK];
    __shared__ int bbits[NBLK];
    __shared__ unsigned char taken[NBLK];
    int tid = threadIdx.x;
    double s = 0.0;
    for (int i = 0; i < BLOCK_TOK; ++i) s += timpD[tid * BLOCK_TOK + i];
    bimp[tid] = s;
    taken[tid] = 0;
    __syncthreads();
    if (tid == 0) {
        int kb[4], tot = 0;
        for (int g = 0; g < 4; ++g) { kb[g] = (int)rint(64.0 * (double)ratio[g]); tot += kb[g]; }
        kb[3] += NBLK - tot;
        int c0 = kb[0], c1 = kb[0] + kb[1], c2 = kb[0] + kb[1] + kb[2];
        for (int r = 0; r < NBLK; ++r) {
            int best = -1; double bv = 0.0;
            for (int b2 = 0; b2 < NBLK; ++b2) {
                if (!taken[b2] && (best < 0 || bimp[b2] > bv)) { bv = bimp[b2]; best = b2; }
            }
            taken[best] = 1;
            int g = (r >= c0) + (r >= c1) + (r >= c2);
            bbits[best] = 8 >> g;
        }
    }
    __syncthreads();
    float lev = (float)((1 << bbits[tid]) - 1);
    for (int i = 0; i < BLOCK_TOK; ++i) levels_tok[tid * BLOCK_TOK + i] = lev;
}

// ---------------------------------------------------------------------------
// Fake quant f64, narrowing in place (f64 row -> f32 at row base).
// ---------------------------------------------------------------------------
__global__ __launch_bounds__(64) void fakequant(double* __restrict__ kD,
                                                double* __restrict__ vD,
                                                const float* __restrict__ levels_tok) {
    int row = blockIdx.x;
    double lev = (double)levels_tok[row >> 3];
    int lane = threadIdx.x;
    #pragma unroll
    for (int which = 0; which < 2; ++which) {
        double* p = (which ? vD : kD) + (size_t)row * DH;
        double x0 = p[lane], x1 = p[lane + 64];
        double mn = fmin(x0, x1), mx = fmax(x0, x1);
        #pragma unroll
        for (int o = 1; o < 64; o <<= 1) {
            mn = fmin(mn, __shfl_xor(mn, o));
            mx = fmax(mx, __shfl_xor(mx, o));
        }
        double scale = fmax((mx - mn) / lev, 1e-8);
        double q0 = rint((x0 - mn) / scale) * scale + mn;
        double q1 = rint((x1 - mn) / scale) * scale + mn;
        __syncthreads();
        float* f = (float*)p;
        f[lane]      = (float)q0;
        f[lane + 64] = (float)q1;
        __syncthreads();
    }
}

// ---------------------------------------------------------------------------
// cvt kernels: quantized K/V (f32 views, row stride 256 floats) -> split bf16.
// K: dense [S*NKVH*DH]; V: transposed [NKVH][DH][S] for PV B-fragments.
// ---------------------------------------------------------------------------
__global__ __launch_bounds__(256) void cvt_k(const float* __restrict__ kf,
                                             u16* __restrict__ kHi,
                                             u16* __restrict__ kLo) {
    size_t i = (size_t)blockIdx.x * 256 + threadIdx.x;   // i indexes float4
    size_t g = i * 4;
    size_t row = g >> 7, d = g & 127;
    float4 v = *reinterpret_cast<const float4*>(kf + (row << 8) + d);
    float fv[4] = {v.x, v.y, v.z, v.w};
    u16 hb[4], lb[4];
    #pragma unroll
    for (int j = 0; j < 4; ++j) {
        hb[j] = f2bf_rne(fv[j]);
        lb[j] = f2bf_rne(fv[j] - bf2f(hb[j]));
    }
    uint2 H = {(unsigned)hb[0] | ((unsigned)hb[1] << 16),
               (unsigned)hb[2] | ((unsigned)hb[3] << 16)};
    uint2 L = {(unsigned)lb[0] | ((unsigned)lb[1] << 16),
               (unsigned)lb[2] | ((unsigned)lb[3] << 16)};
    reinterpret_cast<uint2*>(kHi)[i] = H;
    reinterpret_cast<uint2*>(kLo)[i] = L;
}

__global__ __launch_bounds__(256) void cvt_vT(const float* __restrict__ vf,
                                              u16* __restrict__ vTHi,
                                              u16* __restrict__ vTLo) {
    __shared__ float T[32][132];
    const int kvh = blockIdx.x;
    const int s0 = blockIdx.y * 32;
    const int tid = threadIdx.x;
    {
        int r = tid >> 3, d0 = (tid & 7) * 16;
        const float* src = vf + (((size_t)(s0 + r) * NKVH + kvh) << 8) + d0;
        #pragma unroll
        for (int j = 0; j < 4; ++j)
            *reinterpret_cast<float4*>(&T[r][d0 + 4 * j]) =
                *reinterpret_cast<const float4*>(&src[4 * j]);
    }
    __syncthreads();
    int d = tid >> 1, sc = (tid & 1) * 16;
    u16 hb[16], lb[16];
    #pragma unroll
    for (int t = 0; t < 16; ++t) {
        float x = T[sc + t][d];
        hb[t] = f2bf_rne(x);
        lb[t] = f2bf_rne(x - bf2f(hb[t]));
    }
    u16* oh = vTHi + (size_t)(kvh * DH + d) * S + s0 + sc;
    u16* ol = vTLo + (size_t)(kvh * DH + d) * S + s0 + sc;
    uint4 w;
    w.x = (unsigned)hb[0] | ((unsigned)hb[1] << 16);
    w.y = (unsigned)hb[2] | ((unsigned)hb[3] << 16);
    w.z = (unsigned)hb[4] | ((unsigned)hb[5] << 16);
    w.w = (unsigned)hb[6] | ((unsigned)hb[7] << 16);
    *reinterpret_cast<uint4*>(oh) = w;
    w.x = (unsigned)hb[8]  | ((unsigned)hb[9]  << 16);
    w.y = (unsigned)hb[10] | ((unsigned)hb[11] << 16);
    w.z = (unsigned)hb[12] | ((unsigned)hb[13] << 16);
    w.w = (unsigned)hb[14] | ((unsigned)hb[15] << 16);
    *reinterpret_cast<uint4*>(oh + 8) = w;
    w.x = (unsigned)lb[0] | ((unsigned)lb[1] << 16);
    w.y = (unsigned)lb[2] | ((unsigned)lb[3] << 16);
    w.z = (unsigned)lb[4] | ((unsigned)lb[5] << 16);
    w.w = (unsigned)lb[6] | ((unsigned)lb[7] << 16);
    *reinterpret_cast<uint4*>(ol) = w;
    w.x = (unsigned)lb[8]  | ((unsigned)lb[9]  << 16);
    w.y = (unsigned)lb[10] | ((unsigned)lb[11] << 16);
    w.z = (unsigned)lb[12] | ((unsigned)lb[13] << 16);
    w.w = (unsigned)lb[14] | ((unsigned)lb[15] << 16);
    *reinterpret_cast<uint4*>(ol + 8) = w;
}

// ---------------------------------------------------------------------------
// MFMA flash attention (split-bf16). One block = (head, 32-row q-tile),
// 4 waves: wave w owns P frag (fi=w>>1, fj=w&1) and O rows fi*16.., cols
// (w&1)*64... Q frags hoisted to registers. XOR-swizzled LDS tiles.
// ctx written in place over q.
// ---------------------------------------------------------------------------
__global__ __launch_bounds__(256) void attn_mfma(float* qb,
                                                 const u16* __restrict__ kHi,
                                                 const u16* __restrict__ kLo,
                                                 const u16* __restrict__ vTHi,
                                                 const u16* __restrict__ vTLo) {
    const float SCALING = 0.08838834764831843f;
    const int h = blockIdx.x, qt = blockIdx.y;
    const int q0 = qt * QB, kvh = h >> 2;
    const int tid = threadIdx.x, lane = tid & 63, w = tid >> 6;
    const int fi = w >> 1, fjw = w & 1;
    const int l15 = lane & 15, lg = lane >> 4;

    __shared__ __align__(16) u16 Qh[32][128], Ql[32][128];
    __shared__ __align__(16) u16 Kh[32][128], Kl[32][128];
    __shared__ __align__(16) u16 Vh[128][32], Vl[128][32];
    __shared__ __align__(16) u16 Ph[32][32], Pl[32][32];
    __shared__ float rmax[2][2][16];
    __shared__ float rsum[2][2][16];

    // ---- stage Q once: f32 -> split bf16, swizzled ----
    {
        int r = tid >> 3, c2 = (tid & 7) * 2;
        const float* src = qb + (size_t)(q0 + r) * HID + h * DH + c2 * 8;
        float fv[16];
        #pragma unroll
        for (int j = 0; j < 4; ++j) {
            float4 t4 = *reinterpret_cast<const float4*>(src + 4 * j);
            fv[4 * j + 0] = t4.x; fv[4 * j + 1] = t4.y;
            fv[4 * j + 2] = t4.z; fv[4 * j + 3] = t4.w;
        }
        u16 hi[16], lo[16];
        #pragma unroll
        for (int j = 0; j < 16; ++j) {
            hi[j] = f2bf_rne(fv[j]);
            lo[j] = f2bf_rne(fv[j] - bf2f(hi[j]));
        }
        #pragma unroll
        for (int j = 0; j < 2; ++j) {
            int sl = c2 + j;
            int ph = (sl ^ (r & 15)) * 8;
            uint4 wv;
            wv.x = (unsigned)hi[8 * j + 0] | ((unsigned)hi[8 * j + 1] << 16);
            wv.y = (unsigned)hi[8 * j + 2] | ((unsigned)hi[8 * j + 3] << 16);
            wv.z = (unsigned)hi[8 * j + 4] | ((unsigned)hi[8 * j + 5] << 16);
            wv.w = (unsigned)hi[8 * j + 6] | ((unsigned)hi[8 * j + 7] << 16);
            *reinterpret_cast<uint4*>(&Qh[r][ph]) = wv;
            wv.x = (unsigned)lo[8 * j + 0] | ((unsigned)lo[8 * j + 1] << 16);
            wv.y = (unsigned)lo[8 * j + 2] | ((unsigned)lo[8 * j + 3] << 16);
            wv.z = (unsigned)lo[8 * j + 4] | ((unsigned)lo[8 * j + 5] << 16);
            wv.w = (unsigned)lo[8 * j + 6] | ((unsigned)lo[8 * j + 7] << 16);
            *reinterpret_cast<uint4*>(&Ql[r][ph]) = wv;
        }
    }
    __syncthreads();
    bf16x8 qh[4], qlr[4];
    {
        int qr = fi * 16 + l15;
        #pragma unroll
        for (int kg = 0; kg < 4; ++kg) {
            int ph = ((kg * 4 + lg) ^ (qr & 15)) * 8;
            qh[kg]  = *reinterpret_cast<const bf16x8*>(&Qh[qr][ph]);
            qlr[kg] = *reinterpret_cast<const bf16x8*>(&Ql[qr][ph]);
        }
    }

    float mrun[4] = {-INFINITY, -INFINITY, -INFINITY, -INFINITY};
    float lrun[4] = {0.f, 0.f, 0.f, 0.f};
    f32x4 oAcc[4];
    #pragma unroll
    for (int cf = 0; cf < 4; ++cf) oAcc[cf] = (f32x4){0.f, 0.f, 0.f, 0.f};

    for (int kt = 0; kt <= qt; ++kt) {
        const int kbase = kt * QB;
        __syncthreads();   // previous tile's K/V/P reads complete
        {   // stage K (32x128 hi/lo)
            int r = tid >> 3, c2 = (tid & 7) * 2;
            const u16* sh = kHi + ((size_t)(kbase + r) * NKVH + kvh) * DH;
            const u16* sl_ = kLo + ((size_t)(kbase + r) * NKVH + kvh) * DH;
            #pragma unroll
            for (int j = 0; j < 2; ++j) {
                int sl = c2 + j;
                int ph = (sl ^ (r & 15)) * 8;
                *reinterpret_cast<uint4*>(&Kh[r][ph]) =
                    *reinterpret_cast<const uint4*>(&sh[sl * 8]);
                *reinterpret_cast<uint4*>(&Kl[r][ph]) =
                    *reinterpret_cast<const uint4*>(&sl_[sl * 8]);
            }
            // stage Vt (128x32 hi/lo)
            int d = tid >> 1, s2 = (tid & 1) * 2;
            const u16* vh_ = vTHi + (size_t)(kvh * DH + d) * S + kbase;
            const u16* vl_ = vTLo + (size_t)(kvh * DH + d) * S + kbase;
            #pragma unroll
            for (int j = 0; j < 2; ++j) {
                int sl = s2 + j;
                int ph = (sl ^ (d & 3)) * 8;
                *reinterpret_cast<uint4*>(&Vh[d][ph]) =
                    *reinterpret_cast<const uint4*>(&vh_[sl * 8]);
                *reinterpret_cast<uint4*>(&Vl[d][ph]) =
                    *reinterpret_cast<const uint4*>(&vl_[sl * 8]);
            }
        }
        __syncthreads();

        // ---- QK^T (12 MFMA) ----
        f32x4 s = (f32x4){0.f, 0.f, 0.f, 0.f};
        {
            int kr = fjw * 16 + l15;
            #pragma unroll
            for (int kg = 0; kg < 4; ++kg) {
                int ph = ((kg * 4 + lg) ^ (kr & 15)) * 8;
                bf16x8 kh = *reinterpret_cast<const bf16x8*>(&Kh[kr][ph]);
                bf16x8 kl = *reinterpret_cast<const bf16x8*>(&Kl[kr][ph]);
                s = __builtin_amdgcn_mfma_f32_16x16x32_bf16(qh[kg], kh, s, 0, 0, 0);
                s = __builtin_amdgcn_mfma_f32_16x16x32_bf16(qlr[kg], kh, s, 0, 0, 0);
                s = __builtin_amdgcn_mfma_f32_16x16x32_bf16(qh[kg], kl, s, 0, 0, 0);
            }
        }

        // ---- mask + scale + fragment row-max ----
        float sv[4], fm4[4];
        #pragma unroll
        for (int r = 0; r < 4; ++r) {
            float x = s[r] * SCALING;
            int rowg = q0 + fi * 16 + lg * 4 + r;
            int colg = kbase + fjw * 16 + l15;
            sv[r] = (colg > rowg) ? -INFINITY : x;
            float t = sv[r];
            t = fmaxf(t, __shfl_xor(t, 1));
            t = fmaxf(t, __shfl_xor(t, 2));
            t = fmaxf(t, __shfl_xor(t, 4));
            t = fmaxf(t, __shfl_xor(t, 8));
            fm4[r] = t;
        }
        if (l15 == 0) {
            #pragma unroll
            for (int r = 0; r < 4; ++r) rmax[fi][fjw][lg * 4 + r] = fm4[r];
        }
        __syncthreads();

        // ---- online softmax update ----
        float c4[4], p4[4], u4[4];
        #pragma unroll
        for (int r = 0; r < 4; ++r) {
            float mt = fmaxf(fm4[r], rmax[fi][fjw ^ 1][lg * 4 + r]);
            float mn = fmaxf(mrun[r], mt);
            c4[r] = expf(mrun[r] - mn);
            p4[r] = expf(sv[r] - mn);
            mrun[r] = mn;
            float u = p4[r];
            u += __shfl_xor(u, 1);
            u += __shfl_xor(u, 2);
            u += __shfl_xor(u, 4);
            u += __shfl_xor(u, 8);
            u4[r] = u;
        }
        if (l15 == 0) {
            #pragma unroll
            for (int r = 0; r < 4; ++r) rsum[fi][fjw][lg * 4 + r] = u4[r];
        }
        // write P (split bf16, swizzled)
        #pragma unroll
        for (int r = 0; r < 4; ++r) {
            int prow = fi * 16 + lg * 4 + r;
            int pcol = fjw * 16 + l15;
            u16 hi = f2bf_rne(p4[r]);
            u16 lo = f2bf_rne(p4[r] - bf2f(hi));
            int ph = ((pcol >> 3) ^ (prow & 3)) * 8 + (pcol & 7);
            Ph[prow][ph] = hi;
            Pl[prow][ph] = lo;
        }
        __syncthreads();
        #pragma unroll
        for (int r = 0; r < 4; ++r) {
            float ut = u4[r] + rsum[fi][fjw ^ 1][lg * 4 + r];
            lrun[r] = lrun[r] * c4[r] + ut;
            #pragma unroll
            for (int cf = 0; cf < 4; ++cf) oAcc[cf][r] *= c4[r];
        }

        // ---- PV (12 MFMA) ----
        {
            int pr = fi * 16 + l15;
            int php = (lg ^ (pr & 3)) * 8;
            bf16x8 pa = *reinterpret_cast<const bf16x8*>(&Ph[pr][php]);
            bf16x8 pb = *reinterpret_cast<const bf16x8*>(&Pl[pr][php]);
            #pragma unroll
            for (int cf = 0; cf < 4; ++cf) {
                int d = fjw * 64 + cf * 16 + l15;
                int vp = (lg ^ (d & 3)) * 8;
                bf16x8 vh = *reinterpret_cast<const bf16x8*>(&Vh[d][vp]);
                bf16x8 vl = *reinterpret_cast<const bf16x8*>(&Vl[d][vp]);
                oAcc[cf] = __builtin_amdgcn_mfma_f32_16x16x32_bf16(pa, vh, oAcc[cf], 0, 0, 0);
                oAcc[cf] = __builtin_amdgcn_mfma_f32_16x16x32_bf16(pb, vh, oAcc[cf], 0, 0, 0);
                oAcc[cf] = __builtin_amdgcn_mfma_f32_16x16x32_bf16(pa, vl, oAcc[cf], 0, 0, 0);
            }
        }
    }

    float inv4[4];
    #pragma unroll
    for (int r = 0; r < 4; ++r) inv4[r] = 1.0f / lrun[r];
    #pragma unroll
    for (int cf = 0; cf < 4; ++cf)
        #pragma unroll
        for (int r = 0; r < 4; ++r) {
            int rowg = q0 + fi * 16 + lg * 4 + r;
            int d = fjw * 64 + cf * 16 + l15;
            qb[(size_t)rowg * HID + h * DH + d] = oAcc[cf][r] * inv4[r];
        }
}

// ---------------------------------------------------------------------------
extern "C" void kernel_launch(void* const* d_in, const int* in_sizes, int n_in,
                              void* d_out, int out_size, void* d_ws, size_t ws_size,
                              hipStream_t stream) {
    const float* hs    = (const float*)d_in[0];
    const float* cosT  = (const float*)d_in[1];
    const float* sinT  = (const float*)d_in[2];
    /* d_in[3] attention_mask: pure causal, reconstructed analytically */
    const float* ratio = (const float*)d_in[4];
    const float* Wq    = (const float*)d_in[5];
    const float* Wk    = (const float*)d_in[6];
    const float* Wv    = (const float*)d_in[7];
    const float* Wo    = (const float*)d_in[8];
    float* out = (float*)d_out;

    // ws layout (~95 MB): f64 first, then f32, then bf16 arrays (16B aligned).
    double* kD     = (double*)d_ws;                      // 2,097,152 f64
    double* vD     = kD + (size_t)S * NKVH * DH;         // 2,097,152 f64
    double* qlastD = vD + (size_t)S * NKVH * DH;         // 81,920    f64
    double* awD    = qlastD + (size_t)LAST * HID;        // 1,310,720 f64
    double* timpD  = awD + (size_t)NH * LAST * S;        // 2048      f64
    float*  qbuf   = (float*)(timpD + S);                // 8,388,608 f32
    float*  levels = qbuf + (size_t)S * HID;             // 2048      f32
    u16*    kHi    = (u16*)(levels + S);                 // 2,097,152 u16 each
    u16*    kLo    = kHi + (size_t)S * NKVH * DH;
    u16*    vTHi   = kLo + (size_t)S * NKVH * DH;
    u16*    vTLo   = vTHi + (size_t)S * NKVH * DH;

    dim3 blk(256);
    gemm_split<<<dim3(HID / 128, S / 128), blk, 0, stream>>>(hs, Wq, qbuf, S, HID, HID);
    gemm_f64acc<<<dim3((NKVH * DH) / 64, S / 64), blk, 0, stream>>>(hs, Wk, kD, S, NKVH * DH, HID);
    gemm_f64acc<<<dim3((NKVH * DH) / 64, S / 64), blk, 0, stream>>>(hs, Wv, vD, S, NKVH * DH, HID);

    rope_q<<<(S * NH * 64) / 256, blk, 0, stream>>>(qbuf, cosT, sinT);
    rope_kD<<<(S * NKVH * 64) / 256, blk, 0, stream>>>(kD, cosT, sinT);

    qlast_f64<<<HID / 64, blk, 0, stream>>>(hs, Wq, qlastD);
    rope_qlastD<<<(LAST * NH * 64 + 255) / 256, blk, 0, stream>>>(qlastD, cosT, sinT);
    imp_scores64<<<dim3(NH, LAST), blk, 0, stream>>>(qlastD, kD, awD);
    imp_finish64<<<S / 256, blk, 0, stream>>>(awD, timpD);
    bits_alloc<<<1, 64, 0, stream>>>(timpD, ratio, levels);
    fakequant<<<S * NKVH, 64, 0, stream>>>(kD, vD, levels);

    cvt_k<<<(S * NKVH * DH / 4) / 256, blk, 0, stream>>>((const float*)kD, kHi, kLo);
    cvt_vT<<<dim3(NKVH, S / 32), blk, 0, stream>>>((const float*)vD, vTHi, vTLo);

    attn_mfma<<<dim3(NH, S / QB), blk, 0, stream>>>(qbuf, kHi, kLo, vTHi, vTLo);

    gemm_split<<<dim3(HID / 128, S / 128), blk, 0, stream>>>(qbuf, Wo, out, S, HID, HID);
}

// Round 13
// 2497.008 us; speedup vs baseline: 2.4899x; 1.0828x over previous
//
#include <hip/hip_runtime.h>
#include <hip/hip_bf16.h>
#include <cmath>

#define S 2048
#define HID 4096
#define NH 32
#define NKVH 8
#define DH 128
#define LAST 20
#define BLOCK_TOK 32
#define NBLK 64  /* S / BLOCK_TOK */
#define QB 32    /* flash q-tile */

typedef __attribute__((ext_vector_type(8))) short bf16x8;
typedef __attribute__((ext_vector_type(4))) float f32x4;
typedef unsigned short u16;

static __device__ __forceinline__ u16 f2bf_rne(float x) {
    unsigned int u = __float_as_uint(x);
    unsigned int r = (u + 0x7FFFu + ((u >> 16) & 1u)) >> 16;
    return (u16)r;
}
static __device__ __forceinline__ float bf2f(u16 h) {
    return __uint_as_float(((unsigned int)h) << 16);
}

// ---------------------------------------------------------------------------
// Split-bf16 MFMA GEMM (post-decision paths: Q-proj, O-proj). VALIDATED r6-r12.
// ---------------------------------------------------------------------------
__global__ __launch_bounds__(256) void gemm_split(const float* __restrict__ A,
                                                  const float* __restrict__ B,
                                                  float* __restrict__ C,
                                                  int M, int N, int K) {
    __shared__ __align__(16) unsigned char smem[32768];
    unsigned char* Ab = smem;
    unsigned char* Bb = smem + 16384;
    const int tid = threadIdx.x;
    const int bx = blockIdx.x * 128;
    const int by = blockIdx.y * 128;
    const int lane = tid & 63, wid = tid >> 6;
    const int wm = wid >> 1, wn = wid & 1;
    const int l15 = lane & 15, lg = lane >> 4;

    const int ar = tid >> 1, akh = tid & 1;
    const int bcol = tid & 127, bks = tid >> 7;

    f32x4 acc[4][4];
    #pragma unroll
    for (int i = 0; i < 4; ++i)
        #pragma unroll
        for (int j = 0; j < 4; ++j)
            acc[i][j] = (f32x4){0.f, 0.f, 0.f, 0.f};

    for (int k0 = 0; k0 < K; k0 += 32) {
        {
            const float* ap = A + (size_t)(by + ar) * K + k0 + akh * 16;
            float fv[16];
            #pragma unroll
            for (int j = 0; j < 4; ++j) {
                float4 t4 = *reinterpret_cast<const float4*>(ap + 4 * j);
                fv[4 * j + 0] = t4.x; fv[4 * j + 1] = t4.y;
                fv[4 * j + 2] = t4.z; fv[4 * j + 3] = t4.w;
            }
            u16 hi[16], lo[16];
            #pragma unroll
            for (int j = 0; j < 16; ++j) {
                hi[j] = f2bf_rne(fv[j]);
                lo[j] = f2bf_rne(fv[j] - bf2f(hi[j]));
            }
            uint4 w;
            unsigned char* rp = Ab + ar * 128;
            const int m7 = ar & 7;
            w.x = (unsigned)hi[0] | ((unsigned)hi[1] << 16);
            w.y = (unsigned)hi[2] | ((unsigned)hi[3] << 16);
            w.z = (unsigned)hi[4] | ((unsigned)hi[5] << 16);
            w.w = (unsigned)hi[6] | ((unsigned)hi[7] << 16);
            *reinterpret_cast<uint4*>(rp + (((akh * 2 + 0) ^ m7) << 4)) = w;
            w.x = (unsigned)hi[8]  | ((unsigned)hi[9]  << 16);
            w.y = (unsigned)hi[10] | ((unsigned)hi[11] << 16);
            w.z = (unsigned)hi[12] | ((unsigned)hi[13] << 16);
            w.w = (unsigned)hi[14] | ((unsigned)hi[15] << 16);
            *reinterpret_cast<uint4*>(rp + (((akh * 2 + 1) ^ m7) << 4)) = w;
            w.x = (unsigned)lo[0] | ((unsigned)lo[1] << 16);
            w.y = (unsigned)lo[2] | ((unsigned)lo[3] << 16);
            w.z = (unsigned)lo[4] | ((unsigned)lo[5] << 16);
            w.w = (unsigned)lo[6] | ((unsigned)lo[7] << 16);
            *reinterpret_cast<uint4*>(rp + (((akh * 2 + 4) ^ m7) << 4)) = w;
            w.x = (unsigned)lo[8]  | ((unsigned)lo[9]  << 16);
            w.y = (unsigned)lo[10] | ((unsigned)lo[11] << 16);
            w.z = (unsigned)lo[12] | ((unsigned)lo[13] << 16);
            w.w = (unsigned)lo[14] | ((unsigned)lo[15] << 16);
            *reinterpret_cast<uint4*>(rp + (((akh * 2 + 5) ^ m7) << 4)) = w;
        }
        {
            const float* bp = B + (size_t)(k0 + bks * 16) * N + bx + bcol;
            float fv[16];
            #pragma unroll
            for (int j = 0; j < 16; ++j) fv[j] = bp[(size_t)j * N];
            u16 hi[16], lo[16];
            #pragma unroll
            for (int j = 0; j < 16; ++j) {
                hi[j] = f2bf_rne(fv[j]);
                lo[j] = f2bf_rne(fv[j] - bf2f(hi[j]));
            }
            uint4 w;
            unsigned char* cp = Bb + bcol * 128;
            const int m7 = bcol & 7;
            w.x = (unsigned)hi[0] | ((unsigned)hi[1] << 16);
            w.y = (unsigned)hi[2] | ((unsigned)hi[3] << 16);
            w.z = (unsigned)hi[4] | ((unsigned)hi[5] << 16);
            w.w = (unsigned)hi[6] | ((unsigned)hi[7] << 16);
            *reinterpret_cast<uint4*>(cp + (((bks * 2 + 0) ^ m7) << 4)) = w;
            w.x = (unsigned)hi[8]  | ((unsigned)hi[9]  << 16);
            w.y = (unsigned)hi[10] | ((unsigned)hi[11] << 16);
            w.z = (unsigned)hi[12] | ((unsigned)hi[13] << 16);
            w.w = (unsigned)hi[14] | ((unsigned)hi[15] << 16);
            *reinterpret_cast<uint4*>(cp + (((bks * 2 + 1) ^ m7) << 4)) = w;
            w.x = (unsigned)lo[0] | ((unsigned)lo[1] << 16);
            w.y = (unsigned)lo[2] | ((unsigned)lo[3] << 16);
            w.z = (unsigned)lo[4] | ((unsigned)lo[5] << 16);
            w.w = (unsigned)lo[6] | ((unsigned)lo[7] << 16);
            *reinterpret_cast<uint4*>(cp + (((bks * 2 + 4) ^ m7) << 4)) = w;
            w.x = (unsigned)lo[8]  | ((unsigned)lo[9]  << 16);
            w.y = (unsigned)lo[10] | ((unsigned)lo[11] << 16);
            w.z = (unsigned)lo[12] | ((unsigned)lo[13] << 16);
            w.w = (unsigned)lo[14] | ((unsigned)lo[15] << 16);
            *reinterpret_cast<uint4*>(cp + (((bks * 2 + 5) ^ m7) << 4)) = w;
        }
        __syncthreads();
        bf16x8 ah[4], al[4], bh[4], bl[4];
        #pragma unroll
        for (int f = 0; f < 4; ++f) {
            const int R = wm * 64 + f * 16 + l15;
            const unsigned char* rp = Ab + R * 128;
            const int m7 = R & 7;
            ah[f] = *reinterpret_cast<const bf16x8*>(rp + ((lg ^ m7) << 4));
            al[f] = *reinterpret_cast<const bf16x8*>(rp + (((lg + 4) ^ m7) << 4));
            const int Cc = wn * 64 + f * 16 + l15;
            const unsigned char* cp = Bb + Cc * 128;
            const int c7 = Cc & 7;
            bh[f] = *reinterpret_cast<const bf16x8*>(cp + ((lg ^ c7) << 4));
            bl[f] = *reinterpret_cast<const bf16x8*>(cp + (((lg + 4) ^ c7) << 4));
        }
        __syncthreads();
        #pragma unroll
        for (int mf = 0; mf < 4; ++mf)
            #pragma unroll
            for (int nf = 0; nf < 4; ++nf) {
                acc[mf][nf] = __builtin_amdgcn_mfma_f32_16x16x32_bf16(
                    ah[mf], bh[nf], acc[mf][nf], 0, 0, 0);
                acc[mf][nf] = __builtin_amdgcn_mfma_f32_16x16x32_bf16(
                    al[mf], bh[nf], acc[mf][nf], 0, 0, 0);
                acc[mf][nf] = __builtin_amdgcn_mfma_f32_16x16x32_bf16(
                    ah[mf], bl[nf], acc[mf][nf], 0, 0, 0);
            }
    }
    #pragma unroll
    for (int mf = 0; mf < 4; ++mf) {
        #pragma unroll
        for (int nf = 0; nf < 4; ++nf) {
            const int col = bx + wn * 64 + nf * 16 + l15;
            #pragma unroll
            for (int r = 0; r < 4; ++r) {
                const int row = by + wm * 64 + mf * 16 + lg * 4 + r;
                C[(size_t)row * N + col] = acc[mf][nf][r];
            }
        }
    }
}

// ---------------------------------------------------------------------------
// Fused f64-accumulation K+V projection GEMM (decision path).
// Grid (32,32): bx<16 -> Wk->kD cols bx*64; else Wv->vD cols (bx-16)*64.
// 64x64 tile, BK=16, pair micro-tile: conflict-free double2 LDS reads,
// per-element serial k-order fma identical to r7-r12 (same numerics).
// ---------------------------------------------------------------------------
__global__ __launch_bounds__(256) void gemm_f64_kv(const float* __restrict__ hs,
                                                   const float* __restrict__ Wk,
                                                   const float* __restrict__ Wv,
                                                   double* __restrict__ kD,
                                                   double* __restrict__ vD) {
    const int BM = 64, BN = 64, BK = 16;
    const int N = NKVH * DH;   // 1024
    const int K = HID;
    __shared__ __align__(16) double As[BK][BM + 2];
    __shared__ __align__(16) double Bs[BK][BN + 2];
    const int tid = threadIdx.x;
    const int tx = tid & 15, ty = tid >> 4;
    const int by = blockIdx.y * BM;
    const bool isV = blockIdx.x >= 16;
    const float* B = isV ? Wv : Wk;
    double* C = isV ? vD : kD;
    const int bx = (isV ? blockIdx.x - 16 : blockIdx.x) * BN;

    double acc[4][4] = {};

    for (int k0 = 0; k0 < K; k0 += BK) {
        #pragma unroll
        for (int i = 0; i < 4; ++i) {
            int idx = tid + i * 256;
            int ar = idx >> 4, ac = idx & 15;
            As[ac][ar] = (double)hs[(size_t)(by + ar) * K + k0 + ac];
            int br = idx >> 6, bc = idx & 63;
            Bs[br][bc] = (double)B[(size_t)(k0 + br) * N + bx + bc];
        }
        __syncthreads();
        #pragma unroll
        for (int kk = 0; kk < BK; ++kk) {
            double2 a0 = *reinterpret_cast<const double2*>(&As[kk][ty * 2]);
            double2 a1 = *reinterpret_cast<const double2*>(&As[kk][ty * 2 + 32]);
            double2 b0 = *reinterpret_cast<const double2*>(&Bs[kk][tx * 2]);
            double2 b1 = *reinterpret_cast<const double2*>(&Bs[kk][tx * 2 + 32]);
            double av[4] = {a0.x, a0.y, a1.x, a1.y};
            double bv[4] = {b0.x, b0.y, b1.x, b1.y};
            #pragma unroll
            for (int i = 0; i < 4; ++i)
                #pragma unroll
                for (int j = 0; j < 4; ++j)
                    acc[i][j] = fma(av[i], bv[j], acc[i][j]);
        }
        __syncthreads();
    }
    #pragma unroll
    for (int i = 0; i < 4; ++i) {
        int row = by + ty * 2 + (i & 1) + (i >> 1) * 32;
        double2 c0, c1;
        c0.x = acc[i][0]; c0.y = acc[i][1];
        c1.x = acc[i][2]; c1.y = acc[i][3];
        *reinterpret_cast<double2*>(&C[(size_t)row * N + bx + tx * 2]) = c0;
        *reinterpret_cast<double2*>(&C[(size_t)row * N + bx + tx * 2 + 32]) = c1;
    }
}

// ---------------------------------------------------------------------------
// RoPE: q (f32, in place) and kD (f64, in place).
// ---------------------------------------------------------------------------
__global__ __launch_bounds__(256) void rope_q(float* __restrict__ q,
                                              const float* __restrict__ cosT,
                                              const float* __restrict__ sinT) {
    int idx = blockIdx.x * 256 + threadIdx.x;
    int t = idx / (NH * 64);
    int rem = idx % (NH * 64);
    int h = rem >> 6, d = rem & 63;
    float c1 = cosT[t * DH + d], s1 = sinT[t * DH + d];
    float c2 = cosT[t * DH + d + 64], s2 = sinT[t * DH + d + 64];
    float* base = q + (size_t)t * HID + h * DH;
    float x1 = base[d], x2 = base[d + 64];
    base[d]      = x1 * c1 - x2 * s1;
    base[d + 64] = x2 * c2 + x1 * s2;
}

__global__ __launch_bounds__(256) void rope_kD(double* __restrict__ kD,
                                               const float* __restrict__ cosT,
                                               const float* __restrict__ sinT) {
    int idx = blockIdx.x * 256 + threadIdx.x;
    int t = idx / (NKVH * 64);
    int rem = idx % (NKVH * 64);
    int h = rem >> 6, d = rem & 63;
    double c1 = (double)cosT[t * DH + d], s1 = (double)sinT[t * DH + d];
    double c2 = (double)cosT[t * DH + d + 64], s2 = (double)sinT[t * DH + d + 64];
    double* base = kD + ((size_t)t * NKVH + h) * DH;
    double x1 = base[d], x2 = base[d + 64];
    base[d]      = x1 * c1 - x2 * s1;
    base[d + 64] = x2 * c2 + x1 * s2;
}

// ---------------------------------------------------------------------------
// qlastD = hs[last 20] @ Wq (f64 acc, Wq read once).
// ---------------------------------------------------------------------------
__global__ __launch_bounds__(256) void qlast_f64(const float* __restrict__ hs,
                                                 const float* __restrict__ Wq,
                                                 double* __restrict__ qlastD) {
    __shared__ float hsC[LAST][128];
    __shared__ float WqC[128][65];
    const int tid = threadIdx.x;
    const int n0 = blockIdx.x * 64;
    const int nc = tid & 63;
    const int jg = tid >> 6;
    double acc[5] = {};

    for (int k0 = 0; k0 < HID; k0 += 128) {
        for (int e = tid; e < LAST * 128; e += 256) {
            int j = e >> 7, kk = e & 127;
            hsC[j][kk] = hs[(size_t)(S - LAST + j) * HID + k0 + kk];
        }
        for (int e = tid; e < 128 * 64; e += 256) {
            int r = e >> 6, c = e & 63;
            WqC[r][c] = Wq[(size_t)(k0 + r) * HID + n0 + c];
        }
        __syncthreads();
        #pragma unroll 4
        for (int kk = 0; kk < 128; ++kk) {
            double w = (double)WqC[kk][nc];
            #pragma unroll
            for (int jj = 0; jj < 5; ++jj)
                acc[jj] = fma((double)hsC[jg * 5 + jj][kk], w, acc[jj]);
        }
        __syncthreads();
    }
    #pragma unroll
    for (int jj = 0; jj < 5; ++jj)
        qlastD[(size_t)(jg * 5 + jj) * HID + n0 + nc] = acc[jj];
}

__global__ __launch_bounds__(256) void rope_qlastD(double* __restrict__ qD,
                                                   const float* __restrict__ cosT,
                                                   const float* __restrict__ sinT) {
    int idx = blockIdx.x * 256 + threadIdx.x;
    if (idx >= LAST * NH * 64) return;
    int j = idx / (NH * 64);
    int rem = idx % (NH * 64);
    int h = rem >> 6, d = rem & 63;
    int t = S - LAST + j;
    double c1 = (double)cosT[t * DH + d], s1 = (double)sinT[t * DH + d];
    double c2 = (double)cosT[t * DH + d + 64], s2 = (double)sinT[t * DH + d + 64];
    double* base = qD + (size_t)j * HID + h * DH;
    double x1 = base[d], x2 = base[d + 64];
    base[d]      = x1 * c1 - x2 * s1;
    base[d + 64] = x2 * c2 + x1 * s2;
}

// ---------------------------------------------------------------------------
// Importance scores f64 (pre-quant kD), then reduce.
// ---------------------------------------------------------------------------
__global__ __launch_bounds__(256) void imp_scores64(const double* __restrict__ qlastD,
                                                    const double* __restrict__ kD,
                                                    double* __restrict__ awD) {
    const double SC = 0.08838834764831843;
    const int h = blockIdx.x, j = blockIdx.y;
    const int qpos = S - LAST + j;
    const int kvh = h >> 2;
    const int tid = threadIdx.x;
    const int lane = tid & 63, wid = tid >> 6;
    __shared__ double qs[DH];
    __shared__ double redA[4], redB[4];
    if (tid < DH) qs[tid] = qlastD[(size_t)j * HID + h * DH + tid];
    __syncthreads();

    double sloc[8];
    int cnt = 0;
    double lmax = -1e300;
    for (int kp = tid; kp <= qpos; kp += 256) {
        const double* kr = kD + ((size_t)kp * NKVH + kvh) * DH;
        double s = 0.0;
        #pragma unroll 8
        for (int d = 0; d < DH; ++d) s = fma(qs[d], kr[d], s);
        s *= SC;
        sloc[cnt++] = s;
        lmax = fmax(lmax, s);
    }
    #pragma unroll
    for (int o = 32; o > 0; o >>= 1) lmax = fmax(lmax, __shfl_xor(lmax, o));
    if (lane == 0) redA[wid] = lmax;
    __syncthreads();
    double gmax = fmax(fmax(redA[0], redA[1]), fmax(redA[2], redA[3]));
    double lsum = 0.0;
    for (int i = 0; i < cnt; ++i) lsum += exp(sloc[i] - gmax);
    #pragma unroll
    for (int o = 32; o > 0; o >>= 1) lsum += __shfl_xor(lsum, o);
    if (lane == 0) redB[wid] = lsum;
    __syncthreads();
    double inv = 1.0 / (redB[0] + redB[1] + redB[2] + redB[3]);
    double* ar = awD + (size_t)(h * LAST + j) * S;
    int i = 0;
    for (int kp = tid; kp < S; kp += 256) {
        double val = 0.0;
        if (kp <= qpos) { val = exp(sloc[i] - gmax) * inv; ++i; }
        ar[kp] = val;
    }
}

__global__ __launch_bounds__(256) void imp_finish64(const double* __restrict__ awD,
                                                    double* __restrict__ timpD) {
    int kp = blockIdx.x * 256 + threadIdx.x;
    double s = 0.0;
    for (int r = 0; r < NH * LAST; ++r) s += awD[(size_t)r * S + kp];
    int cntv = (kp >= S - LAST) ? (S - kp) : LAST;
    timpD[kp] = s / (double)cntv;
}

// ---------------------------------------------------------------------------
// Block importance -> stable argsort -> per-token levels.
// ---------------------------------------------------------------------------
__global__ __launch_bounds__(64) void bits_alloc(const double* __restrict__ timpD,
                                                 const float* __restrict__ ratio,
                                                 float* __restrict__ levels_tok) {
    __shared__ double bimp[NBLK];
    __shared__ int bbits[NBLK];
    __shared__ unsigned char taken[NBLK];
    int tid = threadIdx.x;
    double s = 0.0;
    for (int i = 0; i < BLOCK_TOK; ++i) s += timpD[tid * BLOCK_TOK + i];
    bimp[tid] = s;
    taken[tid] = 0;
    __syncthreads();
    if (tid == 0) {
        int kb[4], tot = 0;
        for (int g = 0; g < 4; ++g) { kb[g] = (int)rint(64.0 * (double)ratio[g]); tot += kb[g]; }
        kb[3] += NBLK - tot;
        int c0 = kb[0], c1 = kb[0] + kb[1], c2 = kb[0] + kb[1] + kb[2];
        for (int r = 0; r < NBLK; ++r) {
            int best = -1; double bv = 0.0;
            for (int b2 = 0; b2 < NBLK; ++b2) {
                if (!taken[b2] && (best < 0 || bimp[b2] > bv)) { bv = bimp[b2]; best = b2; }
            }
            taken[best] = 1;
            int g = (r >= c0) + (r >= c1) + (r >= c2);
            bbits[best] = 8 >> g;
        }
    }
    __syncthreads();
    float lev = (float)((1 << bbits[tid]) - 1);
    for (int i = 0; i < BLOCK_TOK; ++i) levels_tok[tid * BLOCK_TOK + i] = lev;
}

// ---------------------------------------------------------------------------
// Fake quant f64, narrowing in place (f64 row -> f32 at row base).
// ---------------------------------------------------------------------------
__global__ __launch_bounds__(64) void fakequant(double* __restrict__ kD,
                                                double* __restrict__ vD,
                                                const float* __restrict__ levels_tok) {
    int row = blockIdx.x;
    double lev = (double)levels_tok[row >> 3];
    int lane = threadIdx.x;
    #pragma unroll
    for (int which = 0; which < 2; ++which) {
        double* p = (which ? vD : kD) + (size_t)row * DH;
        double x0 = p[lane], x1 = p[lane + 64];
        double mn = fmin(x0, x1), mx = fmax(x0, x1);
        #pragma unroll
        for (int o = 1; o < 64; o <<= 1) {
            mn = fmin(mn, __shfl_xor(mn, o));
            mx = fmax(mx, __shfl_xor(mx, o));
        }
        double scale = fmax((mx - mn) / lev, 1e-8);
        double q0 = rint((x0 - mn) / scale) * scale + mn;
        double q1 = rint((x1 - mn) / scale) * scale + mn;
        __syncthreads();
        float* f = (float*)p;
        f[lane]      = (float)q0;
        f[lane + 64] = (float)q1;
        __syncthreads();
    }
}

// ---------------------------------------------------------------------------
// cvt kernels: quantized K/V (f32 views, row stride 256 floats) -> split bf16.
// K: dense [S*NKVH*DH]; V: transposed [NKVH][DH][S] for PV B-fragments.
// ---------------------------------------------------------------------------
__global__ __launch_bounds__(256) void cvt_k(const float* __restrict__ kf,
                                             u16* __restrict__ kHi,
                                             u16* __restrict__ kLo) {
    size_t i = (size_t)blockIdx.x * 256 + threadIdx.x;   // i indexes float4
    size_t g = i * 4;
    size_t row = g >> 7, d = g & 127;
    float4 v = *reinterpret_cast<const float4*>(kf + (row << 8) + d);
    float fv[4] = {v.x, v.y, v.z, v.w};
    u16 hb[4], lb[4];
    #pragma unroll
    for (int j = 0; j < 4; ++j) {
        hb[j] = f2bf_rne(fv[j]);
        lb[j] = f2bf_rne(fv[j] - bf2f(hb[j]));
    }
    uint2 H = {(unsigned)hb[0] | ((unsigned)hb[1] << 16),
               (unsigned)hb[2] | ((unsigned)hb[3] << 16)};
    uint2 L = {(unsigned)lb[0] | ((unsigned)lb[1] << 16),
               (unsigned)lb[2] | ((unsigned)lb[3] << 16)};
    reinterpret_cast<uint2*>(kHi)[i] = H;
    reinterpret_cast<uint2*>(kLo)[i] = L;
}

__global__ __launch_bounds__(256) void cvt_vT(const float* __restrict__ vf,
                                              u16* __restrict__ vTHi,
                                              u16* __restrict__ vTLo) {
    __shared__ float T[32][132];
    const int kvh = blockIdx.x;
    const int s0 = blockIdx.y * 32;
    const int tid = threadIdx.x;
    {
        int r = tid >> 3, d0 = (tid & 7) * 16;
        const float* src = vf + (((size_t)(s0 + r) * NKVH + kvh) << 8) + d0;
        #pragma unroll
        for (int j = 0; j < 4; ++j)
            *reinterpret_cast<float4*>(&T[r][d0 + 4 * j]) =
                *reinterpret_cast<const float4*>(&src[4 * j]);
    }
    __syncthreads();
    int d = tid >> 1, sc = (tid & 1) * 16;
    u16 hb[16], lb[16];
    #pragma unroll
    for (int t = 0; t < 16; ++t) {
        float x = T[sc + t][d];
        hb[t] = f2bf_rne(x);
        lb[t] = f2bf_rne(x - bf2f(hb[t]));
    }
    u16* oh = vTHi + (size_t)(kvh * DH + d) * S + s0 + sc;
    u16* ol = vTLo + (size_t)(kvh * DH + d) * S + s0 + sc;
    uint4 w;
    w.x = (unsigned)hb[0] | ((unsigned)hb[1] << 16);
    w.y = (unsigned)hb[2] | ((unsigned)hb[3] << 16);
    w.z = (unsigned)hb[4] | ((unsigned)hb[5] << 16);
    w.w = (unsigned)hb[6] | ((unsigned)hb[7] << 16);
    *reinterpret_cast<uint4*>(oh) = w;
    w.x = (unsigned)hb[8]  | ((unsigned)hb[9]  << 16);
    w.y = (unsigned)hb[10] | ((unsigned)hb[11] << 16);
    w.z = (unsigned)hb[12] | ((unsigned)hb[13] << 16);
    w.w = (unsigned)hb[14] | ((unsigned)hb[15] << 16);
    *reinterpret_cast<uint4*>(oh + 8) = w;
    w.x = (unsigned)lb[0] | ((unsigned)lb[1] << 16);
    w.y = (unsigned)lb[2] | ((unsigned)lb[3] << 16);
    w.z = (unsigned)lb[4] | ((unsigned)lb[5] << 16);
    w.w = (unsigned)lb[6] | ((unsigned)lb[7] << 16);
    *reinterpret_cast<uint4*>(ol) = w;
    w.x = (unsigned)lb[8]  | ((unsigned)lb[9]  << 16);
    w.y = (unsigned)lb[10] | ((unsigned)lb[11] << 16);
    w.z = (unsigned)lb[12] | ((unsigned)lb[13] << 16);
    w.w = (unsigned)lb[14] | ((unsigned)lb[15] << 16);
    *reinterpret_cast<uint4*>(ol + 8) = w;
}

// ---------------------------------------------------------------------------
// MFMA flash attention (split-bf16). One block = (head, 32-row q-tile),
// 4 waves. Q frags hoisted to registers. XOR-swizzled LDS tiles.
// ctx written in place over q. VALIDATED r12.
// ---------------------------------------------------------------------------
__global__ __launch_bounds__(256) void attn_mfma(float* qb,
                                                 const u16* __restrict__ kHi,
                                                 const u16* __restrict__ kLo,
                                                 const u16* __restrict__ vTHi,
                                                 const u16* __restrict__ vTLo) {
    const float SCALING = 0.08838834764831843f;
    const int h = blockIdx.x, qt = blockIdx.y;
    const int q0 = qt * QB, kvh = h >> 2;
    const int tid = threadIdx.x, lane = tid & 63, w = tid >> 6;
    const int fi = w >> 1, fjw = w & 1;
    const int l15 = lane & 15, lg = lane >> 4;

    __shared__ __align__(16) u16 Qh[32][128], Ql[32][128];
    __shared__ __align__(16) u16 Kh[32][128], Kl[32][128];
    __shared__ __align__(16) u16 Vh[128][32], Vl[128][32];
    __shared__ __align__(16) u16 Ph[32][32], Pl[32][32];
    __shared__ float rmax[2][2][16];
    __shared__ float rsum[2][2][16];

    // ---- stage Q once: f32 -> split bf16, swizzled ----
    {
        int r = tid >> 3, c2 = (tid & 7) * 2;
        const float* src = qb + (size_t)(q0 + r) * HID + h * DH + c2 * 8;
        float fv[16];
        #pragma unroll
        for (int j = 0; j < 4; ++j) {
            float4 t4 = *reinterpret_cast<const float4*>(src + 4 * j);
            fv[4 * j + 0] = t4.x; fv[4 * j + 1] = t4.y;
            fv[4 * j + 2] = t4.z; fv[4 * j + 3] = t4.w;
        }
        u16 hi[16], lo[16];
        #pragma unroll
        for (int j = 0; j < 16; ++j) {
            hi[j] = f2bf_rne(fv[j]);
            lo[j] = f2bf_rne(fv[j] - bf2f(hi[j]));
        }
        #pragma unroll
        for (int j = 0; j < 2; ++j) {
            int sl = c2 + j;
            int ph = (sl ^ (r & 15)) * 8;
            uint4 wv;
            wv.x = (unsigned)hi[8 * j + 0] | ((unsigned)hi[8 * j + 1] << 16);
            wv.y = (unsigned)hi[8 * j + 2] | ((unsigned)hi[8 * j + 3] << 16);
            wv.z = (unsigned)hi[8 * j + 4] | ((unsigned)hi[8 * j + 5] << 16);
            wv.w = (unsigned)hi[8 * j + 6] | ((unsigned)hi[8 * j + 7] << 16);
            *reinterpret_cast<uint4*>(&Qh[r][ph]) = wv;
            wv.x = (unsigned)lo[8 * j + 0] | ((unsigned)lo[8 * j + 1] << 16);
            wv.y = (unsigned)lo[8 * j + 2] | ((unsigned)lo[8 * j + 3] << 16);
            wv.z = (unsigned)lo[8 * j + 4] | ((unsigned)lo[8 * j + 5] << 16);
            wv.w = (unsigned)lo[8 * j + 6] | ((unsigned)lo[8 * j + 7] << 16);
            *reinterpret_cast<uint4*>(&Ql[r][ph]) = wv;
        }
    }
    __syncthreads();
    bf16x8 qh[4], qlr[4];
    {
        int qr = fi * 16 + l15;
        #pragma unroll
        for (int kg = 0; kg < 4; ++kg) {
            int ph = ((kg * 4 + lg) ^ (qr & 15)) * 8;
            qh[kg]  = *reinterpret_cast<const bf16x8*>(&Qh[qr][ph]);
            qlr[kg] = *reinterpret_cast<const bf16x8*>(&Ql[qr][ph]);
        }
    }

    float mrun[4] = {-INFINITY, -INFINITY, -INFINITY, -INFINITY};
    float lrun[4] = {0.f, 0.f, 0.f, 0.f};
    f32x4 oAcc[4];
    #pragma unroll
    for (int cf = 0; cf < 4; ++cf) oAcc[cf] = (f32x4){0.f, 0.f, 0.f, 0.f};

    for (int kt = 0; kt <= qt; ++kt) {
        const int kbase = kt * QB;
        __syncthreads();   // previous tile's K/V/P reads complete
        {   // stage K (32x128 hi/lo)
            int r = tid >> 3, c2 = (tid & 7) * 2;
            const u16* sh = kHi + ((size_t)(kbase + r) * NKVH + kvh) * DH;
            const u16* sl_ = kLo + ((size_t)(kbase + r) * NKVH + kvh) * DH;
            #pragma unroll
            for (int j = 0; j < 2; ++j) {
                int sl = c2 + j;
                int ph = (sl ^ (r & 15)) * 8;
                *reinterpret_cast<uint4*>(&Kh[r][ph]) =
                    *reinterpret_cast<const uint4*>(&sh[sl * 8]);
                *reinterpret_cast<uint4*>(&Kl[r][ph]) =
                    *reinterpret_cast<const uint4*>(&sl_[sl * 8]);
            }
            // stage Vt (128x32 hi/lo)
            int d = tid >> 1, s2 = (tid & 1) * 2;
            const u16* vh_ = vTHi + (size_t)(kvh * DH + d) * S + kbase;
            const u16* vl_ = vTLo + (size_t)(kvh * DH + d) * S + kbase;
            #pragma unroll
            for (int j = 0; j < 2; ++j) {
                int sl = s2 + j;
                int ph = (sl ^ (d & 3)) * 8;
                *reinterpret_cast<uint4*>(&Vh[d][ph]) =
                    *reinterpret_cast<const uint4*>(&vh_[sl * 8]);
                *reinterpret_cast<uint4*>(&Vl[d][ph]) =
                    *reinterpret_cast<const uint4*>(&vl_[sl * 8]);
            }
        }
        __syncthreads();

        // ---- QK^T (12 MFMA) ----
        f32x4 s = (f32x4){0.f, 0.f, 0.f, 0.f};
        {
            int kr = fjw * 16 + l15;
            #pragma unroll
            for (int kg = 0; kg < 4; ++kg) {
                int ph = ((kg * 4 + lg) ^ (kr & 15)) * 8;
                bf16x8 kh = *reinterpret_cast<const bf16x8*>(&Kh[kr][ph]);
                bf16x8 kl = *reinterpret_cast<const bf16x8*>(&Kl[kr][ph]);
                s = __builtin_amdgcn_mfma_f32_16x16x32_bf16(qh[kg], kh, s, 0, 0, 0);
                s = __builtin_amdgcn_mfma_f32_16x16x32_bf16(qlr[kg], kh, s, 0, 0, 0);
                s = __builtin_amdgcn_mfma_f32_16x16x32_bf16(qh[kg], kl, s, 0, 0, 0);
            }
        }

        // ---- mask + scale + fragment row-max ----
        float sv[4], fm4[4];
        #pragma unroll
        for (int r = 0; r < 4; ++r) {
            float x = s[r] * SCALING;
            int rowg = q0 + fi * 16 + lg * 4 + r;
            int colg = kbase + fjw * 16 + l15;
            sv[r] = (colg > rowg) ? -INFINITY : x;
            float t = sv[r];
            t = fmaxf(t, __shfl_xor(t, 1));
            t = fmaxf(t, __shfl_xor(t, 2));
            t = fmaxf(t, __shfl_xor(t, 4));
            t = fmaxf(t, __shfl_xor(t, 8));
            fm4[r] = t;
        }
        if (l15 == 0) {
            #pragma unroll
            for (int r = 0; r < 4; ++r) rmax[fi][fjw][lg * 4 + r] = fm4[r];
        }
        __syncthreads();

        // ---- online softmax update ----
        float c4[4], p4[4], u4[4];
        #pragma unroll
        for (int r = 0; r < 4; ++r) {
            float mt = fmaxf(fm4[r], rmax[fi][fjw ^ 1][lg * 4 + r]);
            float mn = fmaxf(mrun[r], mt);
            c4[r] = expf(mrun[r] - mn);
            p4[r] = expf(sv[r] - mn);
            mrun[r] = mn;
            float u = p4[r];
            u += __shfl_xor(u, 1);
            u += __shfl_xor(u, 2);
            u += __shfl_xor(u, 4);
            u += __shfl_xor(u, 8);
            u4[r] = u;
        }
        if (l15 == 0) {
            #pragma unroll
            for (int r = 0; r < 4; ++r) rsum[fi][fjw][lg * 4 + r] = u4[r];
        }
        // write P (split bf16, swizzled)
        #pragma unroll
        for (int r = 0; r < 4; ++r) {
            int prow = fi * 16 + lg * 4 + r;
            int pcol = fjw * 16 + l15;
            u16 hi = f2bf_rne(p4[r]);
            u16 lo = f2bf_rne(p4[r] - bf2f(hi));
            int ph = ((pcol >> 3) ^ (prow & 3)) * 8 + (pcol & 7);
            Ph[prow][ph] = hi;
            Pl[prow][ph] = lo;
        }
        __syncthreads();
        #pragma unroll
        for (int r = 0; r < 4; ++r) {
            float ut = u4[r] + rsum[fi][fjw ^ 1][lg * 4 + r];
            lrun[r] = lrun[r] * c4[r] + ut;
            #pragma unroll
            for (int cf = 0; cf < 4; ++cf) oAcc[cf][r] *= c4[r];
        }

        // ---- PV (12 MFMA) ----
        {
            int pr = fi * 16 + l15;
            int php = (lg ^ (pr & 3)) * 8;
            bf16x8 pa = *reinterpret_cast<const bf16x8*>(&Ph[pr][php]);
            bf16x8 pb = *reinterpret_cast<const bf16x8*>(&Pl[pr][php]);
            #pragma unroll
            for (int cf = 0; cf < 4; ++cf) {
                int d = fjw * 64 + cf * 16 + l15;
                int vp = (lg ^ (d & 3)) * 8;
                bf16x8 vh = *reinterpret_cast<const bf16x8*>(&Vh[d][vp]);
                bf16x8 vl = *reinterpret_cast<const bf16x8*>(&Vl[d][vp]);
                oAcc[cf] = __builtin_amdgcn_mfma_f32_16x16x32_bf16(pa, vh, oAcc[cf], 0, 0, 0);
                oAcc[cf] = __builtin_amdgcn_mfma_f32_16x16x32_bf16(pb, vh, oAcc[cf], 0, 0, 0);
                oAcc[cf] = __builtin_amdgcn_mfma_f32_16x16x32_bf16(pa, vl, oAcc[cf], 0, 0, 0);
            }
        }
    }

    float inv4[4];
    #pragma unroll
    for (int r = 0; r < 4; ++r) inv4[r] = 1.0f / lrun[r];
    #pragma unroll
    for (int cf = 0; cf < 4; ++cf)
        #pragma unroll
        for (int r = 0; r < 4; ++r) {
            int rowg = q0 + fi * 16 + lg * 4 + r;
            int d = fjw * 64 + cf * 16 + l15;
            qb[(size_t)rowg * HID + h * DH + d] = oAcc[cf][r] * inv4[r];
        }
}

// ---------------------------------------------------------------------------
extern "C" void kernel_launch(void* const* d_in, const int* in_sizes, int n_in,
                              void* d_out, int out_size, void* d_ws, size_t ws_size,
                              hipStream_t stream) {
    const float* hs    = (const float*)d_in[0];
    const float* cosT  = (const float*)d_in[1];
    const float* sinT  = (const float*)d_in[2];
    /* d_in[3] attention_mask: pure causal, reconstructed analytically */
    const float* ratio = (const float*)d_in[4];
    const float* Wq    = (const float*)d_in[5];
    const float* Wk    = (const float*)d_in[6];
    const float* Wv    = (const float*)d_in[7];
    const float* Wo    = (const float*)d_in[8];
    float* out = (float*)d_out;

    // ws layout (~95 MB): f64 first, then f32, then bf16 arrays (16B aligned).
    double* kD     = (double*)d_ws;                      // 2,097,152 f64
    double* vD     = kD + (size_t)S * NKVH * DH;         // 2,097,152 f64
    double* qlastD = vD + (size_t)S * NKVH * DH;         // 81,920    f64
    double* awD    = qlastD + (size_t)LAST * HID;        // 1,310,720 f64
    double* timpD  = awD + (size_t)NH * LAST * S;        // 2048      f64
    float*  qbuf   = (float*)(timpD + S);                // 8,388,608 f32
    float*  levels = qbuf + (size_t)S * HID;             // 2048      f32
    u16*    kHi    = (u16*)(levels + S);                 // 2,097,152 u16 each
    u16*    kLo    = kHi + (size_t)S * NKVH * DH;
    u16*    vTHi   = kLo + (size_t)S * NKVH * DH;
    u16*    vTLo   = vTHi + (size_t)S * NKVH * DH;

    dim3 blk(256);
    gemm_split<<<dim3(HID / 128, S / 128), blk, 0, stream>>>(hs, Wq, qbuf, S, HID, HID);
    gemm_f64_kv<<<dim3(32, S / 64), blk, 0, stream>>>(hs, Wk, Wv, kD, vD);

    rope_q<<<(S * NH * 64) / 256, blk, 0, stream>>>(qbuf, cosT, sinT);
    rope_kD<<<(S * NKVH * 64) / 256, blk, 0, stream>>>(kD, cosT, sinT);

    qlast_f64<<<HID / 64, blk, 0, stream>>>(hs, Wq, qlastD);
    rope_qlastD<<<(LAST * NH * 64 + 255) / 256, blk, 0, stream>>>(qlastD, cosT, sinT);
    imp_scores64<<<dim3(NH, LAST), blk, 0, stream>>>(qlastD, kD, awD);
    imp_finish64<<<S / 256, blk, 0, stream>>>(awD, timpD);
    bits_alloc<<<1, 64, 0, stream>>>(timpD, ratio, levels);
    fakequant<<<S * NKVH, 64, 0, stream>>>(kD, vD, levels);

    cvt_k<<<(S * NKVH * DH / 4) / 256, blk, 0, stream>>>((const float*)kD, kHi, kLo);
    cvt_vT<<<dim3(NKVH, S / 32), blk, 0, stream>>>((const float*)vD, vTHi, vTLo);

    attn_mfma<<<dim3(NH, S / QB), blk, 0, stream>>>(qbuf, kHi, kLo, vTHi, vTLo);

    gemm_split<<<dim3(HID / 128, S / 128), blk, 0, stream>>>(qbuf, Wo, out, S, HID, HID);
}